// Round 12
// baseline (3838.953 us; speedup 1.0000x reference)
//
#include <hip/hip_runtime.h>
#include <hip/hip_bf16.h>
#include <math.h>

#define B_ 64
#define T_ 48
#define D_ 16
#define H_ 128
#define NU_ 128
#define LAM_ 0.01f
#define THR_ 0.01f

// output offsets (floats)
#define NSTEP_OUT 44
#define OFF_A (B_*NSTEP_OUT)
#define OFF_B (OFF_A + NSTEP_OUT*B_*D_)
#define OFF_G (OFF_B + NSTEP_OUT*B_*D_)

#define PHI_ROWS 240
#define PHI_STR  (PHI_ROWS*H_)                  // 30720
#define PHIBUF   (B_*PHI_STR)                   // 1966080
#define GW_STR   12288                          // packed 3 x 64x64 lower tiles
#define GBUF     (B_*GW_STR)                    // 786432
#define L_STR    16896                          // 128 cols x 132 rows (row 128 = dinv)
#define LBUF     (B_*L_STR)                     // 1081344
#define PLS_STR  4096
#define PLSBUF   (B_*PLS_STR)                   // 262144

#define QKS 388
#define SCS 264

__device__ __forceinline__ float sigm(float v) { return 1.0f / (1.0f + expf(-v)); }
__device__ __forceinline__ float dot4(float4 a, float4 b) {
    return a.x*b.x + a.y*b.y + a.z*b.z + a.w*b.w;
}
__device__ __forceinline__ float rdlane(float v, int l) {
    return __uint_as_float(__builtin_amdgcn_readlane(__float_as_uint(v), l));
}

// ===========================================================================
// PIPELINED PATH
// k_P(t): [0,64) attn(t+2) | [64,256) gram(t+1) | [256,320) trisolve+epi(t-1)
//         [320,384) factor(t)
// k_Q(t): [0,320) psi(t+2) | [320,448) front(t+3) | [448,512) mix(t)
// ===========================================================================

__global__ __launch_bounds__(256) void k_P(
    float* __restrict__ hv, float* __restrict__ cv,
    const float* __restrict__ gates, float* __restrict__ pls,
    const float* __restrict__ Wqkv, const float* __restrict__ Wout,
    float* __restrict__ z, float* __restrict__ at_g,
    const float* __restrict__ phi, float* __restrict__ Gring,
    float* __restrict__ Lring,
    const float* __restrict__ hml, float* __restrict__ h_mix,
    const float* __restrict__ w_p, const float* __restrict__ b_p,
    float* __restrict__ out, int t)
{
    __shared__ __align__(16) float smem[12416];
    const int tid = threadIdx.x;
    const int bx = blockIdx.x;

    if (bx < 64) {
        // ================= attention for step ta = t+2 =================
        const int ta = t + 2;
        if (ta < 0 || ta > T_ - 2) return;
        const int b = bx;
        const int BDH = B_*D_*H_;
        float* hs = smem;            // [2048]
        float* qk = smem + 2048;     // [16][QKS]
        float* sc = smem + 8256;     // [8][SCS]
        float* cx = smem + 10368;    // [2048]

        float* plsb = pls + ((size_t)(ta&3))*PLSBUF + (size_t)b*PLS_STR;
        const float4* g0 = (const float4*)(gates + b*2048);
        const float4* g1 = (const float4*)(gates + BDH + b*2048);
        const float4* g2 = (const float4*)(gates + 2*BDH + b*2048);
        const float4* g3 = (const float4*)(gates + 3*BDH + b*2048);
        float4* cv4 = (float4*)(cv + b*2048);
        float4* hv4 = (float4*)(hv + b*2048);
        float4* pl0 = (float4*)plsb;
        float4* pl1 = (float4*)(plsb + 16*H_);
        #pragma unroll
        for (int i = 0; i < 2; ++i) {
            int e4 = i*256 + tid;
            float4 jv = g0[e4], iv = g1[e4], fv = g2[e4], ov = g3[e4];
            float4 c = cv4[e4], ho = hv4[e4];
            float4 cn, hn, dl;
            cn.x = c.x*fv.x + iv.x*jv.x; hn.x = ov.x*tanhf(cn.x); dl.x = hn.x - ho.x;
            cn.y = c.y*fv.y + iv.y*jv.y; hn.y = ov.y*tanhf(cn.y); dl.y = hn.y - ho.y;
            cn.z = c.z*fv.z + iv.z*jv.z; hn.z = ov.z*tanhf(cn.z); dl.z = hn.z - ho.z;
            cn.w = c.w*fv.w + iv.w*jv.w; hn.w = ov.w*tanhf(cn.w); dl.w = hn.w - ho.w;
            cv4[e4] = cn; hv4[e4] = hn;
            ((float4*)hs)[e4] = hn;
            pl0[e4] = ho;
            pl1[e4] = dl;
        }
        __syncthreads();

        // qkv = h_var @ Wqkv^T
        {
            const int half = tid >> 7, mt = tid & 127;
            const float4* w0 = (const float4*)(Wqkv + (size_t)(mt*3 + 0)*H_);
            const float4* w1 = (const float4*)(Wqkv + (size_t)(mt*3 + 1)*H_);
            const float4* w2 = (const float4*)(Wqkv + (size_t)(mt*3 + 2)*H_);
            float acc[3][8] = {};
            for (int i4 = 0; i4 < 32; i4++) {
                float4 wa = w0[i4], wb = w1[i4], wc = w2[i4];
                #pragma unroll
                for (int rr = 0; rr < 8; rr++) {
                    float4 h4 = *(const float4*)&hs[(half*8 + rr)*128 + i4*4];
                    acc[0][rr] += dot4(wa, h4);
                    acc[1][rr] += dot4(wb, h4);
                    acc[2][rr] += dot4(wc, h4);
                }
            }
            #pragma unroll
            for (int q = 0; q < 3; q++)
                #pragma unroll
                for (int rr = 0; rr < 8; rr++)
                    qk[(half*8 + rr)*QKS + mt*3 + q] = acc[q][rr];
        }
        __syncthreads();

        // scores
        for (int e = tid; e < 2048; e += 256) {
            int hh2 = e >> 8, qd = (e >> 4) & 15, kd = e & 15;
            float s = 0.f;
            #pragma unroll
            for (int e4 = 0; e4 < 4; e4++)
                s += dot4(*(const float4*)&qk[qd*QKS + hh2*16 + e4*4],
                          *(const float4*)&qk[kd*QKS + 128 + hh2*16 + e4*4]);
            sc[hh2*SCS + qd*16 + kd] = s * 0.25f;
        }
        __syncthreads();

        // softmax + threshold
        if (tid < 128) {
            int hh2 = tid >> 4, qd = tid & 15;
            float mx = -1e30f;
            #pragma unroll
            for (int kd = 0; kd < 16; kd++) mx = fmaxf(mx, sc[hh2*SCS + qd*16 + kd]);
            float ex[16]; float s = 0.f;
            #pragma unroll
            for (int kd = 0; kd < 16; kd++) { ex[kd] = expf(sc[hh2*SCS + qd*16 + kd] - mx); s += ex[kd]; }
            float inv = 1.0f / s;
            #pragma unroll
            for (int kd = 0; kd < 16; kd++) {
                float a = ex[kd]*inv;
                sc[hh2*SCS + qd*16 + kd] = (a >= THR_) ? a : 0.0f;
            }
        }
        __syncthreads();

        // a_t mean over heads
        {
            int qd = tid >> 4, kd = tid & 15;
            float s = 0.f;
            #pragma unroll
            for (int hh2 = 0; hh2 < 8; hh2++) s += sc[hh2*SCS + qd*16 + kd];
            at_g[b*256 + qd*16 + kd] = s * 0.125f;
        }

        // ctx
        for (int e = tid; e < 2048; e += 256) {
            int qd = e >> 7, c = e & 127, hh2 = c >> 4, ee = c & 15;
            float s = 0.f;
            #pragma unroll
            for (int kd = 0; kd < 16; kd++) s += sc[hh2*SCS + qd*16 + kd] * qk[kd*QKS + 256 + hh2*16 + ee];
            cx[qd*128 + c] = s;
        }
        __syncthreads();

        // z = ctx @ Wout^T
        {
            int h = tid & 127, half = tid >> 7;
            const float4* wr = (const float4*)(Wout + (size_t)h*H_);
            float acc[8] = {};
            for (int i4 = 0; i4 < 32; i4++) {
                float4 w4 = wr[i4];
                #pragma unroll
                for (int r = 0; r < 8; r++)
                    acc[r] += dot4(w4, *(const float4*)&cx[(half*8 + r)*128 + i4*4]);
            }
            #pragma unroll
            for (int r = 0; r < 8; r++) z[b*2048 + (half*8 + r)*H_ + h] = acc[r];
        }
    } else if (bx < 256) {
        // ================= gram for step tg = t+1 (reg-prefetched staging) ==
        const int tg = t + 1;
        if (tg < 3 || tg > T_ - 2) return;
        const int tile = (bx - 64) >> 6, b = (bx - 64) & 63;
        const int r0 = (tile >= 1) ? 64 : 0;
        const int c0 = (tile == 2) ? 64 : 0;
        const bool diag = (r0 == c0);
        float* prt = smem;           // [16][64]
        float* pct = smem + 1024;    // [16][64]
        const float* pb   = phi + ((size_t)(tg%3))*PHIBUF + (size_t)b*PHI_STR;
        const float* plsb = pls + ((size_t)(tg&3))*PLSBUF + (size_t)b*PLS_STR;
        const int tr = tid >> 4, tc = tid & 15;
        const int kk = tid >> 4, rr4 = (tid & 15) << 2;
        float acc[4][4] = {};
        float4 vr, vc;

        // preload chunk 0
        {
            const float* src = (kk < 32) ? (plsb + (size_t)kk*H_) : (pb + (size_t)(kk - 32)*H_);
            vr = *(const float4*)&src[r0 + rr4];
            if (!diag) vc = *(const float4*)&src[c0 + rr4];
        }
        for (int kt = 0; kt < 17; kt++) {
            *(float4*)&prt[kk*64 + rr4] = vr;
            if (!diag) *(float4*)&pct[kk*64 + rr4] = vc;
            __syncthreads();
            if (kt < 16) {
                int krow = (kt + 1)*16 + kk;
                const float* src = (krow < 32) ? (plsb + (size_t)krow*H_)
                                               : (pb + (size_t)(krow - 32)*H_);
                vr = *(const float4*)&src[r0 + rr4];
                if (!diag) vc = *(const float4*)&src[c0 + rr4];
            }
            const float* pcb = diag ? prt : pct;
            #pragma unroll
            for (int k2 = 0; k2 < 16; k2++) {
                float4 a4 = *(const float4*)&prt[k2*64 + tr*4];
                float4 b4 = *(const float4*)&pcb[k2*64 + tc*4];
                float av[4] = {a4.x, a4.y, a4.z, a4.w};
                float bv[4] = {b4.x, b4.y, b4.z, b4.w};
                #pragma unroll
                for (int i = 0; i < 4; i++)
                    #pragma unroll
                    for (int j = 0; j < 4; j++)
                        acc[i][j] += av[i]*bv[j];
            }
            __syncthreads();
        }
        float* Gt = Gring + ((size_t)(tg&1))*GBUF + (size_t)b*GW_STR + (size_t)tile*4096;
        #pragma unroll
        for (int i = 0; i < 4; i++) {
            int lr = tr*4 + i;
            float v[4];
            #pragma unroll
            for (int j = 0; j < 4; j++) {
                int lc = tc*4 + j;
                v[j] = acc[i][j] + ((diag && lr == lc) ? LAM_ : 0.0f);
            }
            float4 o; o.x = v[0]; o.y = v[1]; o.z = v[2]; o.w = v[3];
            *(float4*)&Gt[lr*64 + tc*4] = o;
        }
    } else if (bx < 320) {
        // ======= trisolve (L streamed from global) + finalize + epi, tv = t-1
        const int tv = t - 1;
        if (tv < 0 || tv > T_ - 2) return;
        const int b = bx - 256;
        if (tv < 3) {
            if (tid < 128) h_mix[b*128 + tid] = hml[b*128 + tid];
            return;
        }
        float* ys = smem;            // [128] — y, then x in place
        const float* Lb = Lring + ((size_t)(tv&1))*LBUF + (size_t)b*L_STR;

        if (tid < 64) {
            __builtin_amdgcn_s_setprio(1);
            const int lane = tid;
            float hm0 = hml[b*128 + lane];
            float hm1 = hml[b*128 + lane + 64];
            float dv0 = Lb[lane*132 + 128];
            float dv1 = Lb[(lane+64)*132 + 128];
            float acc0 = hm0, acc1 = hm1;

            // ---- forward, cols 0..63 (rows lane, lane+64), 16-col prefetch
            {
                float c0[16], c1[16], n0[16], n1[16];
                #pragma unroll
                for (int k = 0; k < 16; ++k) {
                    c0[k] = Lb[k*132 + lane];
                    c1[k] = Lb[k*132 + lane + 64];
                }
                for (int g = 0; g < 4; ++g) {
                    if (g < 3) {
                        #pragma unroll
                        for (int k = 0; k < 16; ++k) {
                            n0[k] = Lb[(16*(g+1)+k)*132 + lane];
                            n1[k] = Lb[(16*(g+1)+k)*132 + lane + 64];
                        }
                    }
                    const int s = 16*g;
                    #pragma unroll
                    for (int k = 0; k < 16; ++k) {
                        int j = s + k;
                        float yj = rdlane(acc0 * dv0, j);
                        if (lane > j) acc0 -= c0[k]*yj;
                        else if (lane == j) acc0 = yj;
                        acc1 -= c1[k]*yj;
                    }
                    #pragma unroll
                    for (int k = 0; k < 16; ++k) { c0[k] = n0[k]; c1[k] = n1[k]; }
                }
            }
            // ---- forward, cols 64..127 (row lane+64 only)
            {
                float c1[16], n1[16];
                #pragma unroll
                for (int k = 0; k < 16; ++k) c1[k] = Lb[(64+k)*132 + lane + 64];
                for (int g = 0; g < 4; ++g) {
                    if (g < 3) {
                        #pragma unroll
                        for (int k = 0; k < 16; ++k)
                            n1[k] = Lb[(64+16*(g+1)+k)*132 + lane + 64];
                    }
                    #pragma unroll
                    for (int k = 0; k < 16; ++k) {
                        int j = 16*g + k;              // local col (actual 64+j)
                        float yj = rdlane(acc1 * dv1, j);
                        if (lane > j) acc1 -= c1[k]*yj;
                        else if (lane == j) acc1 = yj;
                    }
                    #pragma unroll
                    for (int k = 0; k < 16; ++k) c1[k] = n1[k];
                }
            }
            ys[lane] = acc0;
            ys[lane + 64] = acc1;

            // ---- backward: L^T x = y (per-lane-contiguous float4 reads)
            for (int p = 7; p >= 0; --p) {
                const int s = p*16;
                float br = 0.f, minv = 0.f;
                float lc[16];
                if (lane < 16) {
                    br = ys[s + lane];
                    minv = Lb[(s+lane)*132 + 128];
                    #pragma unroll
                    for (int k4 = 0; k4 < 4; ++k4) {
                        float4 f4 = *(const float4*)&Lb[(s+lane)*132 + s + k4*4];
                        lc[k4*4+0]=f4.x; lc[k4*4+1]=f4.y; lc[k4*4+2]=f4.z; lc[k4*4+3]=f4.w;
                    }
                } else {
                    #pragma unroll
                    for (int k = 0; k < 16; ++k) lc[k] = 0.f;
                }
                float xk[16];
                #pragma unroll
                for (int j = 15; j >= 0; --j) {
                    if (lane == j) br *= minv;
                    float xj = rdlane(br, j);
                    if (lane < j) br -= lc[j]*xj;
                    xk[j] = xj;
                }
                if (lane < 16) ys[s + lane] = br;
                for (int i = lane; i < s; i += 64) {
                    float a = ys[i];
                    #pragma unroll
                    for (int k4 = 0; k4 < 4; ++k4) {
                        float4 f4 = *(const float4*)&Lb[i*132 + s + k4*4];
                        a -= f4.x*xk[k4*4] + f4.y*xk[k4*4+1] + f4.z*xk[k4*4+2] + f4.w*xk[k4*4+3];
                    }
                    ys[i] = a;
                }
            }

            // ---- finalize
            float y0 = ys[lane], y1 = ys[lane + 64];
            float hh0 = hm0 - LAM_*y0, hh1 = hm1 - LAM_*y1;
            h_mix[b*128 + lane]      = hh0;
            h_mix[b*128 + lane + 64] = hh1;
            float pw = hh0 * w_p[lane] + hh1 * w_p[lane + 64];
            for (int off = 32; off; off >>= 1) pw += __shfl_down(pw, off);
            if (lane == 0) out[b*NSTEP_OUT + (tv - 3)] = pw + b_p[0];
            __builtin_amdgcn_s_setprio(0);
        }
        __syncthreads();

        // theta epilogue (all 256 threads)
        {
            const int ts = tv - 3;
            const float* plsb = pls + ((size_t)(tv&3))*PLSBUF + (size_t)b*PLS_STR;
            const float* phb  = phi + ((size_t)(tv%3))*PHIBUF + (size_t)b*PHI_STR;
            const float4* y4  = (const float4*)ys;
            for (int k = tid; k < 272; k += 256) {
                const float* rowp = (k < 32) ? plsb + (size_t)k*H_
                                             : phb + (size_t)(k - 32)*H_;
                const float4* r4 = (const float4*)rowp;
                float th = 0.f;
                #pragma unroll
                for (int i4 = 0; i4 < 32; i4++) th += dot4(r4[i4], y4[i4]);
                if (k < 16)
                    out[OFF_A + ts*(B_*D_) + b*D_ + k] = th;
                else if (k < 32)
                    out[OFF_B + ts*(B_*D_) + b*D_ + (k - 16)] = th;
                else {
                    int p = k - 32, ip = p/15, jj = p%15, jp = jj + (jj >= ip ? 1 : 0);
                    out[OFF_G + ts*(B_*D_*D_) + b*(D_*D_) + ip*D_ + jp] = th;
                }
            }
            if (tid < D_)
                out[OFF_G + ts*(B_*D_*D_) + b*(D_*D_) + tid*D_ + tid] = 0.0f;
        }
    } else {
        // ================= factor (Cholesky) for tf = t ====================
        const int tf = t;
        if (tf < 3 || tf > T_ - 2) return;
        const int b = bx - 320;
        float* Pan = smem;   // double-buffered panel: [2][16 cols][132 rows]

        const int R = tid >> 4, C = tid & 15;
        const bool lower = (C <= R);

        // load packed lower G into registers
        float g[8][8] = {};
        if (lower) {
            const int tsel = (C >= 8) ? 2 : ((R >= 8) ? 1 : 0);
            const float* Gt = Gring + ((size_t)(tf&1))*GBUF + (size_t)b*GW_STR + (size_t)tsel*4096;
            const int lcb = C*8 - ((C >= 8) ? 64 : 0);
            #pragma unroll
            for (int r = 0; r < 8; ++r) {
                const int lr = R*8 + r - ((R >= 8) ? 64 : 0);
                float4 lo = *(const float4*)(Gt + lr*64 + lcb);
                float4 hi = *(const float4*)(Gt + lr*64 + lcb + 4);
                g[r][0]=lo.x; g[r][1]=lo.y; g[r][2]=lo.z; g[r][3]=lo.w;
                g[r][4]=hi.x; g[r][5]=hi.y; g[r][6]=hi.z; g[r][7]=hi.w;
            }
        }

        float* Lb = Lring + ((size_t)(tf&1))*LBUF + (size_t)b*L_STR;

        for (int p = 0; p < 8; ++p) {
            const int s = p*16;
            float* Pc = Pan + (p & 1)*2112;
            // panel write g -> Pc (local cols 0..15)
            if ((C >> 1) == p && R >= 2*p) {
                #pragma unroll
                for (int c = 0; c < 8; ++c) {
                    const int lc = ((C & 1) << 3) + c;
                    float4 lo = {g[0][c], g[1][c], g[2][c], g[3][c]};
                    float4 hi = {g[4][c], g[5][c], g[6][c], g[7][c]};
                    *(float4*)&Pc[lc*132 + R*8]     = lo;
                    *(float4*)&Pc[lc*132 + R*8 + 4] = hi;
                }
            }
            __syncthreads();
            if (tid < 64) {
                const int lane = tid;
                const int r0 = s + lane, r1 = r0 + 64;
                const bool v0 = r0 < 128, v1 = r1 < 128;
                float a0[16], a1[16];
                #pragma unroll
                for (int k = 0; k < 16; ++k) {
                    a0[k] = v0 ? Pc[k*132 + r0] : 0.f;
                    a1[k] = v1 ? Pc[k*132 + r1] : 0.f;
                }
                float myinv = 0.f;
                #pragma unroll
                for (int j = 0; j < 16; ++j) {
                    float piv = rdlane(a0[j], j);
                    float inv = rsqrtf(piv);
                    float dsq = piv * inv;
                    if (lane == j) myinv = inv;
                    a0[j] = (lane == j) ? dsq : a0[j]*inv;
                    a1[j] *= inv;
                    #pragma unroll
                    for (int c = j+1; c < 16; ++c) {
                        float Lcj = rdlane(a0[j], c);
                        a0[c] -= a0[j]*Lcj;
                        a1[c] -= a1[j]*Lcj;
                    }
                }
                if (lane < 16) Pc[lane*132 + 128] = myinv;   // dinv in pad row
                #pragma unroll
                for (int k = 0; k < 16; ++k) {
                    if (v0) Pc[k*132 + r0] = a0[k];
                    if (v1) Pc[k*132 + r1] = a1[k];
                }
            }
            __syncthreads();
            // cooperative coalesced store of factored panel (incl. dinv row)
            {
                const float4* s4 = (const float4*)Pc;
                float4* d4 = (float4*)(Lb + (size_t)s*132);
                for (int e = tid; e < 528; e += 256) d4[e] = s4[e];
            }
            // trailing rank-16 update in registers (prefetched)
            if (lower && C >= 2*(p+1)) {
                const float* colp = Pc;
                float4 r04 = *(const float4*)&colp[R*8];
                float4 r14 = *(const float4*)&colp[R*8 + 4];
                float4 c04 = *(const float4*)&colp[C*8];
                float4 c14 = *(const float4*)&colp[C*8 + 4];
                #pragma unroll
                for (int k = 0; k < 16; ++k) {
                    float lr[8] = {r04.x,r04.y,r04.z,r04.w,r14.x,r14.y,r14.z,r14.w};
                    float lc[8] = {c04.x,c04.y,c04.z,c04.w,c14.x,c14.y,c14.z,c14.w};
                    if (k < 15) {
                        const float* coln = &Pc[(k+1)*132];
                        r04 = *(const float4*)&coln[R*8];
                        r14 = *(const float4*)&coln[R*8 + 4];
                        c04 = *(const float4*)&coln[C*8];
                        c14 = *(const float4*)&coln[C*8 + 4];
                    }
                    #pragma unroll
                    for (int r = 0; r < 8; ++r)
                        #pragma unroll
                        for (int c = 0; c < 8; ++c)
                            g[r][c] -= lr[r]*lc[c];
                }
            }
            // no extra barrier: next panel-write targets the other buffer
        }
    }
}

__global__ __launch_bounds__(256) void k_Q(
    const float* __restrict__ z, const float* __restrict__ at,
    const float* __restrict__ Wpsi, const float* __restrict__ bpsi,
    float* __restrict__ phi,
    const float* __restrict__ x, const float* __restrict__ hv,
    const float* __restrict__ Wj, const float* __restrict__ Wi, const float* __restrict__ Wf, const float* __restrict__ Wo,
    const float* __restrict__ Uj, const float* __restrict__ Ui, const float* __restrict__ Uf, const float* __restrict__ Uo,
    const float* __restrict__ Bj, const float* __restrict__ Bi, const float* __restrict__ Bf, const float* __restrict__ Bo,
    float* __restrict__ gates,
    const float* __restrict__ h_mix, float* __restrict__ c_mix, float* __restrict__ hml,
    const float* __restrict__ uj, const float* __restrict__ ui, const float* __restrict__ uf, const float* __restrict__ uo,
    const float* __restrict__ wj, const float* __restrict__ wi, const float* __restrict__ wf, const float* __restrict__ wo,
    const float* __restrict__ bj, const float* __restrict__ bi, const float* __restrict__ bf_, const float* __restrict__ bo,
    int t)
{
    __shared__ __align__(16) float smem[8448];
    const int tid = threadIdx.x;
    const int bx = blockIdx.x;

    if (bx < 320) {
        // ================= psi for tp = t+2 (6x4 register-blocked) =========
        const int tp = t + 2;
        if (tp < 3 || tp > T_ - 2) return;
        const int pc = bx >> 6, b = bx & 63;
        const int p0 = pc * 48;
        float* zs = smem;           // [2048]
        float* pr = smem + 2048;    // [48][128]

        {
            const float4* zsrc = (const float4*)(z + b*2048);
            #pragma unroll
            for (int i = 0; i < 2; ++i) ((float4*)zs)[i*256 + tid] = zsrc[i*256 + tid];
        }
        __syncthreads();
        for (int e = tid; e < 48*128; e += 256) {
            int pp = e >> 7, c = e & 127;
            int p = p0 + pp, ip = p/15, jj2 = p%15, jp = jj2 + (jj2 >= ip ? 1 : 0);
            pr[pp*128 + c] = zs[ip*128 + c] * zs[jp*128 + c];
        }
        __syncthreads();

        const int hg = tid & 31, pg = tid >> 5;
        const int h0 = hg*4, pp0 = pg*6;
        const float4* w0 = (const float4*)(Wpsi + (size_t)(h0+0)*H_);
        const float4* w1 = (const float4*)(Wpsi + (size_t)(h0+1)*H_);
        const float4* w2 = (const float4*)(Wpsi + (size_t)(h0+2)*H_);
        const float4* w3 = (const float4*)(Wpsi + (size_t)(h0+3)*H_);
        float acc[6][4] = {};
        for (int i4 = 0; i4 < 32; i4++) {
            float4 wa = w0[i4], wb = w1[i4], wc = w2[i4], wd = w3[i4];
            #pragma unroll
            for (int r = 0; r < 6; r++) {
                float4 p4 = *(const float4*)&pr[(pp0 + r)*128 + i4*4];
                acc[r][0] += dot4(wa, p4);
                acc[r][1] += dot4(wb, p4);
                acc[r][2] += dot4(wc, p4);
                acc[r][3] += dot4(wd, p4);
            }
        }
        float4 bb = *(const float4*)&bpsi[h0];
        float* phb = phi + ((size_t)(tp%3))*PHIBUF + (size_t)b*PHI_STR;
        #pragma unroll
        for (int r = 0; r < 6; r++) {
            int pp = pp0 + r, p = p0 + pp;
            int ip = p/15, jj2 = p%15, jp = jj2 + (jj2 >= ip ? 1 : 0);
            float wat = at[b*256 + ip*16 + jp];
            float4 o;
            o.x = tanhf(acc[r][0] + bb.x) * wat;
            o.y = tanhf(acc[r][1] + bb.y) * wat;
            o.z = tanhf(acc[r][2] + bb.z) * wat;
            o.w = tanhf(acc[r][3] + bb.w) * wat;
            *(float4*)&phb[(size_t)p*H_ + h0] = o;
        }
    } else if (bx < 448) {
        // ========= front: var-gate GEMM for tn = t+3 (chunked hsT) =========
        const int tn = t + 3;
        if (tn < 0 || tn > T_ - 2) return;
        float* hsT = smem;            // [64][68]
        float* Ws  = smem + 4352;     // [64][64]
        const int fbx = bx - 320;
        const int kh = fbx & 1, g = (fbx >> 1) & 3, d = fbx >> 3;
        const int k0 = kh * 64;
        const float* W  = (g==0?Wj:(g==1?Wi:(g==2?Wf:Wo))) + (size_t)d*H_*H_;
        const float* U  = (g==0?Uj:(g==1?Ui:(g==2?Uf:Uo))) + d*H_;
        const float* Bp = (g==0?Bj:(g==1?Bi:(g==2?Bf:Bo))) + d*H_;

        const int tb = tid >> 4, tk = tid & 15;
        float acc[4][4] = {};

        for (int hc = 0; hc < 2; hc++) {
            __syncthreads();
            for (int e = tid; e < 64*64; e += 256) {
                int b2 = e >> 6, h2 = e & 63;
                hsT[h2*68 + b2] = hv[(b2*D_ + d)*H_ + hc*64 + h2];
            }
            for (int e = tid; e < 64*64; e += 256) {
                int h2 = e >> 6, kk = e & 63;
                Ws[h2*64 + kk] = W[(hc*64 + h2)*H_ + k0 + kk];
            }
            __syncthreads();
            for (int h2 = 0; h2 < 64; h2++) {
                float4 hb = *(const float4*)&hsT[h2*68 + tb*4];
                float4 wk = *(const float4*)&Ws[h2*64 + tk*4];
                float hbv[4] = {hb.x, hb.y, hb.z, hb.w};
                float wkv[4] = {wk.x, wk.y, wk.z, wk.w};
                #pragma unroll
                for (int a2 = 0; a2 < 4; a2++)
                    #pragma unroll
                    for (int c2 = 0; c2 < 4; c2++)
                        acc[a2][c2] += hbv[a2] * wkv[c2];
            }
        }

        float u4[4], bp4[4];
        #pragma unroll
        for (int c2 = 0; c2 < 4; c2++) { u4[c2] = U[k0 + tk*4 + c2]; bp4[c2] = Bp[k0 + tk*4 + c2]; }

        #pragma unroll
        for (int a2 = 0; a2 < 4; a2++) {
            int b2 = tb*4 + a2;
            float xv = x[(b2*T_ + tn)*D_ + d];
            float4 o;
            float pre[4];
            #pragma unroll
            for (int c2 = 0; c2 < 4; c2++) pre[c2] = acc[a2][c2] + xv*u4[c2] + bp4[c2];
            if (g == 0) { o.x = tanhf(pre[0]); o.y = tanhf(pre[1]); o.z = tanhf(pre[2]); o.w = tanhf(pre[3]); }
            else        { o.x = sigm(pre[0]);  o.y = sigm(pre[1]);  o.z = sigm(pre[2]);  o.w = sigm(pre[3]); }
            *(float4*)&gates[(size_t)g*(B_*D_*H_) + (b2*D_ + d)*H_ + k0 + tk*4] = o;
        }
    } else {
        // ================= mix-LSTM for tm = t =================
        const int tm = t;
        if (tm < 0 || tm > T_ - 2) return;
        const int b = bx - 448;
        float* xs  = smem;
        float* hs2 = smem + 16;
        float* gj  = smem + 144;
        float* gi  = smem + 272;
        float* gf  = smem + 400;
        float* go  = smem + 528;
        const int n = tid & 127, gg = tid >> 7;
        if (tid < 16)  xs[tid]  = x[(b*T_ + tm)*D_ + tid];
        if (tid < 128) hs2[tid] = h_mix[b*NU_ + tid];
        __syncthreads();

        const float* uA = gg ? uf : uj;
        const float* uB = gg ? uo : ui;
        const float* wA = gg ? wf : wj;
        const float* wB = gg ? wo : wi;
        float accA = gg ? bf_[n] : bj[n];
        float accB = gg ? bo[n]  : bi[n];
        #pragma unroll
        for (int d2 = 0; d2 < 16; ++d2) {
            float xv = xs[d2];
            accA += xv * uA[d2*NU_ + n];
            accB += xv * uB[d2*NU_ + n];
        }
        for (int m = 0; m < 128; ++m) {
            float hvv = hs2[m];
            accA += hvv * wA[m*NU_ + n];
            accB += hvv * wB[m*NU_ + n];
        }
        if (gg == 0) { gj[n] = tanhf(accA); gi[n] = sigm(accB); }
        else         { gf[n] = sigm(accA);  go[n] = sigm(accB); }
        __syncthreads();
        if (tid < 128) {
            float cn = gf[tid]*c_mix[b*NU_ + tid] + gi[tid]*gj[tid];
            c_mix[b*NU_ + tid] = cn;
            hml[b*NU_ + tid]   = go[tid]*tanhf(cn);
        }
    }
}

// ===========================================================================
// FALLBACK PATH (round-8 code, used when ws is too small)
// ===========================================================================

__global__ __launch_bounds__(256) void k_X8(
    float* __restrict__ hv, float* __restrict__ cv,
    const float* __restrict__ gates, float* __restrict__ pls,
    const float* __restrict__ Wqkv, const float* __restrict__ Wout,
    float* __restrict__ z, float* __restrict__ at_g,
    const float* __restrict__ phi, float* __restrict__ Gw,
    const float* __restrict__ x, const float* __restrict__ h_mix,
    float* __restrict__ c_mix, float* __restrict__ hml,
    const float* __restrict__ uj, const float* __restrict__ ui, const float* __restrict__ uf, const float* __restrict__ uo,
    const float* __restrict__ wj, const float* __restrict__ wi, const float* __restrict__ wf, const float* __restrict__ wo,
    const float* __restrict__ bj, const float* __restrict__ bi, const float* __restrict__ bf_, const float* __restrict__ bo,
    const float* __restrict__ ybuf, float* __restrict__ out,
    int ta, int tg, int tm, int te)
{
    __shared__ __align__(16) float smem[12416];
    const int tid = threadIdx.x;
    const int bx = blockIdx.x;

    if (bx < 64) {
        if (ta < 0) return;
        const int b = bx;
        const int BDH = B_*D_*H_;
        float* hs = smem;
        float* qk = smem + 2048;
        float* sc = smem + 8256;
        float* cx = smem + 10368;

        float* plsb = pls + ((size_t)(ta&3)*B_ + b)*PLS_STR;
        const float4* g0 = (const float4*)(gates + b*2048);
        const float4* g1 = (const float4*)(gates + BDH + b*2048);
        const float4* g2 = (const float4*)(gates + 2*BDH + b*2048);
        const float4* g3 = (const float4*)(gates + 3*BDH + b*2048);
        float4* cv4 = (float4*)(cv + b*2048);
        float4* hv4 = (float4*)(hv + b*2048);
        float4* pl0 = (float4*)plsb;
        float4* pl1 = (float4*)(plsb + 16*H_);
        #pragma unroll
        for (int i = 0; i < 2; ++i) {
            int e4 = i*256 + tid;
            float4 jv = g0[e4], iv = g1[e4], fv = g2[e4], ov = g3[e4];
            float4 c = cv4[e4], ho = hv4[e4];
            float4 cn, hn, dl;
            cn.x = c.x*fv.x + iv.x*jv.x; hn.x = ov.x*tanhf(cn.x); dl.x = hn.x - ho.x;
            cn.y = c.y*fv.y + iv.y*jv.y; hn.y = ov.y*tanhf(cn.y); dl.y = hn.y - ho.y;
            cn.z = c.z*fv.z + iv.z*jv.z; hn.z = ov.z*tanhf(cn.z); dl.z = hn.z - ho.z;
            cn.w = c.w*fv.w + iv.w*jv.w; hn.w = ov.w*tanhf(cn.w); dl.w = hn.w - ho.w;
            cv4[e4] = cn; hv4[e4] = hn;
            ((float4*)hs)[e4] = hn;
            pl0[e4] = ho;
            pl1[e4] = dl;
        }
        __syncthreads();
        {
            const int half = tid >> 7, mt = tid & 127;
            const float4* w0 = (const float4*)(Wqkv + (size_t)(mt*3 + 0)*H_);
            const float4* w1 = (const float4*)(Wqkv + (size_t)(mt*3 + 1)*H_);
            const float4* w2 = (const float4*)(Wqkv + (size_t)(mt*3 + 2)*H_);
            float acc[3][8] = {};
            for (int i4 = 0; i4 < 32; i4++) {
                float4 wa = w0[i4], wb = w1[i4], wc = w2[i4];
                #pragma unroll
                for (int rr = 0; rr < 8; rr++) {
                    float4 h4 = *(const float4*)&hs[(half*8 + rr)*128 + i4*4];
                    acc[0][rr] += dot4(wa, h4);
                    acc[1][rr] += dot4(wb, h4);
                    acc[2][rr] += dot4(wc, h4);
                }
            }
            #pragma unroll
            for (int q = 0; q < 3; q++)
                #pragma unroll
                for (int rr = 0; rr < 8; rr++)
                    qk[(half*8 + rr)*QKS + mt*3 + q] = acc[q][rr];
        }
        __syncthreads();
        for (int e = tid; e < 2048; e += 256) {
            int hh2 = e >> 8, qd = (e >> 4) & 15, kd = e & 15;
            float s = 0.f;
            #pragma unroll
            for (int e4 = 0; e4 < 4; e4++)
                s += dot4(*(const float4*)&qk[qd*QKS + hh2*16 + e4*4],
                          *(const float4*)&qk[kd*QKS + 128 + hh2*16 + e4*4]);
            sc[hh2*SCS + qd*16 + kd] = s * 0.25f;
        }
        __syncthreads();
        if (tid < 128) {
            int hh2 = tid >> 4, qd = tid & 15;
            float mx = -1e30f;
            #pragma unroll
            for (int kd = 0; kd < 16; kd++) mx = fmaxf(mx, sc[hh2*SCS + qd*16 + kd]);
            float ex[16]; float s = 0.f;
            #pragma unroll
            for (int kd = 0; kd < 16; kd++) { ex[kd] = expf(sc[hh2*SCS + qd*16 + kd] - mx); s += ex[kd]; }
            float inv = 1.0f / s;
            #pragma unroll
            for (int kd = 0; kd < 16; kd++) {
                float a = ex[kd]*inv;
                sc[hh2*SCS + qd*16 + kd] = (a >= THR_) ? a : 0.0f;
            }
        }
        __syncthreads();
        {
            int qd = tid >> 4, kd = tid & 15;
            float s = 0.f;
            #pragma unroll
            for (int hh2 = 0; hh2 < 8; hh2++) s += sc[hh2*SCS + qd*16 + kd];
            at_g[b*256 + qd*16 + kd] = s * 0.125f;
        }
        for (int e = tid; e < 2048; e += 256) {
            int qd = e >> 7, c = e & 127, hh2 = c >> 4, ee = c & 15;
            float s = 0.f;
            #pragma unroll
            for (int kd = 0; kd < 16; kd++) s += sc[hh2*SCS + qd*16 + kd] * qk[kd*QKS + 256 + hh2*16 + ee];
            cx[qd*128 + c] = s;
        }
        __syncthreads();
        {
            int h = tid & 127, half = tid >> 7;
            const float4* wr = (const float4*)(Wout + (size_t)h*H_);
            float acc[8] = {};
            for (int i4 = 0; i4 < 32; i4++) {
                float4 w4 = wr[i4];
                #pragma unroll
                for (int r = 0; r < 8; r++)
                    acc[r] += dot4(w4, *(const float4*)&cx[(half*8 + r)*128 + i4*4]);
            }
            #pragma unroll
            for (int r = 0; r < 8; r++) z[b*2048 + (half*8 + r)*H_ + h] = acc[r];
        }
    } else if (bx < 256) {
        if (tg < 0) return;
        const int tile = (bx - 64) >> 6, b = (bx - 64) & 63;
        const int r0 = (tile >= 1) ? 64 : 0;
        const int c0 = (tile == 2) ? 64 : 0;
        const bool diag = (r0 == c0);
        float* prt = smem;
        float* pct = smem + 1024;
        const float* pb   = phi + (size_t)(tg&1)*PHIBUF + (size_t)b*PHI_STR;
        const float* plsb = pls + ((size_t)(tg&3)*B_ + b)*PLS_STR;
        const int tr = tid >> 4, tc = tid & 15;
        float acc[4][4] = {};
        for (int kt = 0; kt < 17; kt++) {
            __syncthreads();
            for (int e = tid; e < 16*64; e += 256) {
                int kk = e >> 6, rr = e & 63;
                int krow = kt*16 + kk;
                const float* src = (krow < 32) ? (plsb + (size_t)krow*H_)
                                               : (pb + (size_t)(krow - 32)*H_);
                prt[kk*64 + rr] = src[r0 + rr];
                if (!diag) pct[kk*64 + rr] = src[c0 + rr];
            }
            __syncthreads();
            const float* pcb = diag ? prt : pct;
            #pragma unroll
            for (int kk = 0; kk < 16; kk++) {
                float4 a4 = *(const float4*)&prt[kk*64 + tr*4];
                float4 b4 = *(const float4*)&pcb[kk*64 + tc*4];
                float av[4] = {a4.x, a4.y, a4.z, a4.w};
                float bv[4] = {b4.x, b4.y, b4.z, b4.w};
                #pragma unroll
                for (int i = 0; i < 4; i++)
                    #pragma unroll
                    for (int j = 0; j < 4; j++)
                        acc[i][j] += av[i]*bv[j];
            }
        }
        float* Gt = Gw + (size_t)b*GW_STR + (size_t)tile*4096;
        #pragma unroll
        for (int i = 0; i < 4; i++) {
            int lr = tr*4 + i;
            float v[4];
            #pragma unroll
            for (int j = 0; j < 4; j++) {
                int lc = tc*4 + j;
                v[j] = acc[i][j] + ((diag && lr == lc) ? LAM_ : 0.0f);
            }
            float4 o; o.x = v[0]; o.y = v[1]; o.z = v[2]; o.w = v[3];
            *(float4*)&Gt[lr*64 + tc*4] = o;
        }
    } else if (bx < 320) {
        if (tm < 0) return;
        const int b = bx - 256;
        float* xs  = smem;
        float* hs2 = smem + 16;
        float* gj  = smem + 144;
        float* gi  = smem + 272;
        float* gf  = smem + 400;
        float* go  = smem + 528;
        const int n = tid & 127, gg = tid >> 7;
        if (tid < 16)  xs[tid]  = x[(b*T_ + tm)*D_ + tid];
        if (tid < 128) hs2[tid] = h_mix[b*NU_ + tid];
        __syncthreads();
        const float* uA = gg ? uf : uj;
        const float* uB = gg ? uo : ui;
        const float* wA = gg ? wf : wj;
        const float* wB = gg ? wo : wi;
        float accA = gg ? bf_[n] : bj[n];
        float accB = gg ? bo[n]  : bi[n];
        #pragma unroll
        for (int d2 = 0; d2 < 16; ++d2) {
            float xv = xs[d2];
            accA += xv * uA[d2*NU_ + n];
            accB += xv * uB[d2*NU_ + n];
        }
        for (int m = 0; m < 128; ++m) {
            float hvv = hs2[m];
            accA += hvv * wA[m*NU_ + n];
            accB += hvv * wB[m*NU_ + n];
        }
        if (gg == 0) { gj[n] = tanhf(accA); gi[n] = sigm(accB); }
        else         { gf[n] = sigm(accA);  go[n] = sigm(accB); }
        __syncthreads();
        if (tid < 128) {
            float cn = gf[tid]*c_mix[b*NU_ + tid] + gi[tid]*gj[tid];
            c_mix[b*NU_ + tid] = cn;
            hml[b*NU_ + tid]   = go[tid]*tanhf(cn);
        }
    } else {
        if (te < 3) return;
        const int eb = bx - 320, b = eb >> 1, half = eb & 1;
        const int ts = te - 3;
        float* ys = smem;
        if (tid < 128) ys[tid] = ybuf[b*128 + tid];
        __syncthreads();
        const int k = half*136 + tid;
        if (tid < 136) {
            const float* rowp = (k < 32)
                ? pls + ((size_t)(te&3)*B_ + b)*PLS_STR + (size_t)k*H_
                : phi + (size_t)(te&1)*PHIBUF + (size_t)b*PHI_STR + (size_t)(k - 32)*H_;
            const float4* r4 = (const float4*)rowp;
            const float4* y4 = (const float4*)ys;
            float th = 0.f;
            for (int i4 = 0; i4 < 32; i4++) th += dot4(r4[i4], y4[i4]);
            if (k < 16)
                out[OFF_A + ts*(B_*D_) + b*D_ + k] = th;
            else if (k < 32)
                out[OFF_B + ts*(B_*D_) + b*D_ + (k - 16)] = th;
            else {
                int p = k - 32, ip = p/15, jj = p%15, jp = jj + (jj >= ip ? 1 : 0);
                out[OFF_G + ts*(B_*D_*D_) + b*(D_*D_) + ip*D_ + jp] = th;
            }
        }
        if (half == 0 && tid < 16)
            out[OFF_G + ts*(B_*D_*D_) + b*(D_*D_) + tid*D_ + tid] = 0.0f;
    }
}

__global__ __launch_bounds__(256) void k_Y8(
    const float* __restrict__ z, const float* __restrict__ at,
    const float* __restrict__ Wpsi, const float* __restrict__ bpsi,
    float* __restrict__ phi,
    const float* __restrict__ x, const float* __restrict__ hv,
    const float* __restrict__ Wj, const float* __restrict__ Wi, const float* __restrict__ Wf, const float* __restrict__ Wo,
    const float* __restrict__ Uj, const float* __restrict__ Ui, const float* __restrict__ Uf, const float* __restrict__ Uo,
    const float* __restrict__ Bj, const float* __restrict__ Bi, const float* __restrict__ Bf, const float* __restrict__ Bo,
    float* __restrict__ gates,
    const float* __restrict__ Gw, const float* __restrict__ hml, float* __restrict__ h_mix,
    const float* __restrict__ w_p, const float* __restrict__ b_p,
    float* __restrict__ ybuf, float* __restrict__ out,
    int tp, int tf, int tsolve)
{
    __shared__ __align__(16) float smem[17280];
    const int tid = threadIdx.x;
    const int bx = blockIdx.x;

    if (bx < 64) {
        const int b = bx;
        const int ts = tsolve;
        if (ts < 0) return;
        if (ts < 3) {
            if (tid < 128) h_mix[b*128 + tid] = hml[b*128 + tid];
            return;
        }
        float* Ac   = smem;
        float* rv   = smem + 16896;
        float* hm   = smem + 17024;
        float* dinv = smem + 17152;

        const int R = tid >> 4, C = tid & 15;
        const bool lower = (C <= R);

        if (tid < 128) { float v = hml[b*128 + tid]; hm[tid] = v; rv[tid] = v; }

        float g[8][8] = {};
        if (lower) {
            const int tsel = (C >= 8) ? 2 : ((R >= 8) ? 1 : 0);
            const float* Gt = Gw + (size_t)b*GW_STR + (size_t)tsel*4096;
            const int lcb = C*8 - ((C >= 8) ? 64 : 0);
            #pragma unroll
            for (int r = 0; r < 8; ++r) {
                const int lr = R*8 + r - ((R >= 8) ? 64 : 0);
                float4 lo = *(const float4*)(Gt + lr*64 + lcb);
                float4 hi = *(const float4*)(Gt + lr*64 + lcb + 4);
                g[r][0]=lo.x; g[r][1]=lo.y; g[r][2]=lo.z; g[r][3]=lo.w;
                g[r][4]=hi.x; g[r][5]=hi.y; g[r][6]=hi.z; g[r][7]=hi.w;
            }
        }

        for (int p = 0; p < 8; ++p) {
            const int s = p*16;
            if ((C >> 1) == p && R >= 2*p) {
                #pragma unroll
                for (int c = 0; c < 8; ++c) {
                    float4 lo = {g[0][c], g[1][c], g[2][c], g[3][c]};
                    float4 hi = {g[4][c], g[5][c], g[6][c], g[7][c]};
                    *(float4*)&Ac[(C*8 + c)*132 + R*8]     = lo;
                    *(float4*)&Ac[(C*8 + c)*132 + R*8 + 4] = hi;
                }
            }
            __syncthreads();
            if (tid < 64) {
                const int lane = tid;
                const int r0 = s + lane, r1 = r0 + 64;
                const bool v0 = r0 < 128, v1 = r1 < 128;
                float a0[16], a1[16];
                #pragma unroll
                for (int k = 0; k < 16; ++k) {
                    a0[k] = v0 ? Ac[(s+k)*132 + r0] : 0.f;
                    a1[k] = v1 ? Ac[(s+k)*132 + r1] : 0.f;
                }
                float myinv = 0.f;
                #pragma unroll
                for (int j = 0; j < 16; ++j) {
                    float piv = rdlane(a0[j], j);
                    float inv = rsqrtf(piv);
                    float dsq = piv * inv;
                    if (lane == j) myinv = inv;
                    a0[j] = (lane == j) ? dsq : a0[j]*inv;
                    a1[j] *= inv;
                    #pragma unroll
                    for (int c = j+1; c < 16; ++c) {
                        float Lcj = rdlane(a0[j], c);
                        a0[c] -= a0[j]*Lcj;
                        a1[c] -= a1[j]*Lcj;
                    }
                }
                if (lane < 16) dinv[s + lane] = myinv;
                float fr = (lane < 16) ? rv[s + lane] : 0.f;
                float yv[16];
                #pragma unroll
                for (int j = 0; j < 16; ++j) {
                    if (lane == j) fr *= myinv;
                    float yj = rdlane(fr, j);
                    if (lane > j && lane < 16) fr -= a0[j]*yj;
                    yv[j] = yj;
                }
                if (lane < 16) {
                    rv[r0] = fr;
                } else if (v0) {
                    float acc = rv[r0];
                    #pragma unroll
                    for (int k = 0; k < 16; ++k) acc -= a0[k]*yv[k];
                    rv[r0] = acc;
                }
                if (v1) {
                    float acc = rv[r1];
                    #pragma unroll
                    for (int k = 0; k < 16; ++k) acc -= a1[k]*yv[k];
                    rv[r1] = acc;
                }
                #pragma unroll
                for (int k = 0; k < 16; ++k) {
                    if (v0) Ac[(s+k)*132 + r0] = a0[k];
                    if (v1) Ac[(s+k)*132 + r1] = a1[k];
                }
            }
            __syncthreads();
            if (lower && C >= 2*(p+1)) {
                #pragma unroll
                for (int k = 0; k < 16; ++k) {
                    const float* colp = &Ac[(s+k)*132];
                    float4 r04 = *(const float4*)&colp[R*8];
                    float4 r14 = *(const float4*)&colp[R*8 + 4];
                    float4 c04 = *(const float4*)&colp[C*8];
                    float4 c14 = *(const float4*)&colp[C*8 + 4];
                    float lr[8] = {r04.x,r04.y,r04.z,r04.w,r14.x,r14.y,r14.z,r14.w};
                    float lc[8] = {c04.x,c04.y,c04.z,c04.w,c14.x,c14.y,c14.z,c14.w};
                    #pragma unroll
                    for (int r = 0; r < 8; ++r)
                        #pragma unroll
                        for (int c = 0; c < 8; ++c)
                            g[r][c] -= lr[r]*lc[c];
                }
            }
        }

        if (tid >= 64) return;
        const int lane = tid;
        for (int p = 7; p >= 0; --p) {
            const int s = p*16;
            float br = 0.f, minv = 0.f;
            float lc[16];
            if (lane < 16) {
                br = rv[s + lane];
                minv = dinv[s + lane];
                #pragma unroll
                for (int k4 = 0; k4 < 4; ++k4) {
                    float4 f4 = *(const float4*)&Ac[(s+lane)*132 + s + k4*4];
                    lc[k4*4+0]=f4.x; lc[k4*4+1]=f4.y; lc[k4*4+2]=f4.z; lc[k4*4+3]=f4.w;
                }
            } else {
                #pragma unroll
                for (int k = 0; k < 16; ++k) lc[k] = 0.f;
            }
            float xk[16];
            #pragma unroll
            for (int j = 15; j >= 0; --j) {
                if (lane == j) br *= minv;
                float xj = rdlane(br, j);
                if (lane < j) br -= lc[j]*xj;
                xk[j] = xj;
            }
            if (lane < 16) rv[s + lane] = br;
            for (int i = lane; i < s; i += 64) {
                float acc = rv[i];
                #pragma unroll
                for (int k4 = 0; k4 < 4; ++k4) {
                    float4 f4 = *(const float4*)&Ac[i*132 + s + k4*4];
                    acc -= f4.x*xk[k4*4] + f4.y*xk[k4*4+1] + f4.z*xk[k4*4+2] + f4.w*xk[k4*4+3];
                }
                rv[i] = acc;
            }
        }

        float pw = 0.f;
        #pragma unroll
        for (int ii = 0; ii < 2; ++ii) {
            int i = lane + ii*64;
            float y = rv[i];
            float hhat = hm[i] - LAM_ * y;
            h_mix[b*128 + i] = hhat;
            ybuf[b*128 + i] = y;
            pw += hhat * w_p[i];
        }
        for (int off = 32; off; off >>= 1) pw += __shfl_down(pw, off);
        if (lane == 0) out[b*NSTEP_OUT + (ts - 3)] = pw + b_p[0];
    } else if (bx < 384) {
        if (tp < 0) return;
        const int pc = (bx - 64) >> 6, b = (bx - 64) & 63;
        const int p0 = pc * 48;
        float* zs = smem;
        float* pr = smem + 2048;
        {
            const float4* zsrc = (const float4*)(z + b*2048);
            #pragma unroll
            for (int i = 0; i < 2; ++i) ((float4*)zs)[i*256 + tid] = zsrc[i*256 + tid];
        }
        __syncthreads();
        for (int e = tid; e < 48*128; e += 256) {
            int pp = e >> 7, c = e & 127;
            int p = p0 + pp, ip = p/15, jj2 = p%15, jp = jj2 + (jj2 >= ip ? 1 : 0);
            pr[pp*128 + c] = zs[ip*128 + c] * zs[jp*128 + c];
        }
        __syncthreads();
        const int hg = tid & 31, pg = tid >> 5;
        const int h0 = hg*4, pp0 = pg*6;
        const float4* w0 = (const float4*)(Wpsi + (size_t)(h0+0)*H_);
        const float4* w1 = (const float4*)(Wpsi + (size_t)(h0+1)*H_);
        const float4* w2 = (const float4*)(Wpsi + (size_t)(h0+2)*H_);
        const float4* w3 = (const float4*)(Wpsi + (size_t)(h0+3)*H_);
        float acc[6][4] = {};
        for (int i4 = 0; i4 < 32; i4++) {
            float4 wa = w0[i4], wb = w1[i4], wc = w2[i4], wd = w3[i4];
            #pragma unroll
            for (int r = 0; r < 6; r++) {
                float4 p4 = *(const float4*)&pr[(pp0 + r)*128 + i4*4];
                acc[r][0] += dot4(wa, p4);
                acc[r][1] += dot4(wb, p4);
                acc[r][2] += dot4(wc, p4);
                acc[r][3] += dot4(wd, p4);
            }
        }
        float4 bb = *(const float4*)&bpsi[h0];
        float* phb = phi + (size_t)(tp&1)*PHIBUF + (size_t)b*PHI_STR;
        #pragma unroll
        for (int r = 0; r < 6; r++) {
            int pp = pp0 + r, p = p0 + pp;
            int ip = p/15, jj2 = p%15, jp = jj2 + (jj2 >= ip ? 1 : 0);
            float wat = at[b*256 + ip*16 + jp];
            float4 o;
            o.x = tanhf(acc[r][0] + bb.x) * wat;
            o.y = tanhf(acc[r][1] + bb.y) * wat;
            o.z = tanhf(acc[r][2] + bb.z) * wat;
            o.w = tanhf(acc[r][3] + bb.w) * wat;
            *(float4*)&phb[(size_t)p*H_ + h0] = o;
        }
    } else {
        if (tf < 0 || tf > T_ - 2) return;
        float* hsT = smem;
        float* Ws  = smem + 8704;
        const int fbx = bx - 384;
        const int kh = fbx & 1, g = (fbx >> 1) & 3, d = fbx >> 3;
        const int k0 = kh * 64;
        const float* W  = (g==0?Wj:(g==1?Wi:(g==2?Wf:Wo))) + (size_t)d*H_*H_;
        const float* U  = (g==0?Uj:(g==1?Ui:(g==2?Uf:Uo))) + d*H_;
        const float* Bp = (g==0?Bj:(g==1?Bi:(g==2?Bf:Bo))) + d*H_;

        for (int e = tid; e < 64*128; e += 256) {
            int b2 = e >> 7, h2 = e & 127;
            hsT[h2*68 + b2] = hv[(b2*D_ + d)*H_ + h2];
        }
        const int tb = tid >> 4, tk = tid & 15;
        float acc[4][4] = {};
        for (int hc = 0; hc < 2; hc++) {
            __syncthreads();
            for (int e = tid; e < 64*64; e += 256) {
                int h2 = e >> 6, kk = e & 63;
                Ws[h2*64 + kk] = W[(hc*64 + h2)*H_ + k0 + kk];
            }
            __syncthreads();
            for (int h2 = 0; h2 < 64; h2++) {
                float4 hb = *(const float4*)&hsT[(hc*64 + h2)*68 + tb*4];
                float4 wk = *(const float4*)&Ws[h2*64 + tk*4];
                float hbv[4] = {hb.x, hb.y, hb.z, hb.w};
                float wkv[4] = {wk.x, wk.y, wk.z, wk.w};
                #pragma unroll
                for (int a2 = 0; a2 < 4; a2++)
                    #pragma unroll
                    for (int c2 = 0; c2 < 4; c2++)
                        acc[a2][c2] += hbv[a2] * wkv[c2];
            }
        }
        float u4[4], bp4[4];
        #pragma unroll
        for (int c2 = 0; c2 < 4; c2++) { u4[c2] = U[k0 + tk*4 + c2]; bp4[c2] = Bp[k0 + tk*4 + c2]; }
        #pragma unroll
        for (int a2 = 0; a2 < 4; a2++) {
            int b2 = tb*4 + a2;
            float xv = x[(b2*T_ + tf)*D_ + d];
            float4 o;
            float pre[4];
            #pragma unroll
            for (int c2 = 0; c2 < 4; c2++) pre[c2] = acc[a2][c2] + xv*u4[c2] + bp4[c2];
            if (g == 0) { o.x = tanhf(pre[0]); o.y = tanhf(pre[1]); o.z = tanhf(pre[2]); o.w = tanhf(pre[3]); }
            else        { o.x = sigm(pre[0]);  o.y = sigm(pre[1]);  o.z = sigm(pre[2]);  o.w = sigm(pre[3]); }
            *(float4*)&gates[(size_t)g*(B_*D_*H_) + (b2*D_ + d)*H_ + k0 + tk*4] = o;
        }
    }
}

// ---------------------------------------------------------------------------
extern "C" void kernel_launch(void* const* d_in, const int* in_sizes, int n_in,
                              void* d_out, int out_size, void* d_ws, size_t ws_size,
                              hipStream_t stream) {
    const float* x    = (const float*)d_in[0];
    const float* W_j  = (const float*)d_in[1];
    const float* W_i  = (const float*)d_in[2];
    const float* W_f  = (const float*)d_in[3];
    const float* W_o  = (const float*)d_in[4];
    const float* U_j  = (const float*)d_in[5];
    const float* U_i  = (const float*)d_in[6];
    const float* U_f  = (const float*)d_in[7];
    const float* U_o  = (const float*)d_in[8];
    const float* B_j  = (const float*)d_in[9];
    const float* B_i  = (const float*)d_in[10];
    const float* B_f  = (const float*)d_in[11];
    const float* B_o  = (const float*)d_in[12];
    const float* u_j  = (const float*)d_in[13];
    const float* u_i  = (const float*)d_in[14];
    const float* u_f  = (const float*)d_in[15];
    const float* u_o  = (const float*)d_in[16];
    const float* w_j  = (const float*)d_in[17];
    const float* w_i  = (const float*)d_in[18];
    const float* w_f  = (const float*)d_in[19];
    const float* w_o  = (const float*)d_in[20];
    const float* b_j  = (const float*)d_in[21];
    const float* b_i  = (const float*)d_in[22];
    const float* b_f  = (const float*)d_in[23];
    const float* b_o  = (const float*)d_in[24];
    const float* W_qkv= (const float*)d_in[25];
    const float* W_out= (const float*)d_in[26];
    const float* W_psi= (const float*)d_in[27];
    const float* b_psi= (const float*)d_in[28];
    const float* w_p  = (const float*)d_in[29];
    const float* b_p  = (const float*)d_in[30];

    float* out = (float*)d_out;
    float* ws = (float*)d_ws;

    const size_t NEED = (size_t)11640832 * 4;   // 46.6 MB

    if (ws_size >= NEED) {
        // ================= pipelined path =================
        float* hv    = ws;                   // 131072
        float* cv    = hv + 131072;          // 131072
        float* h_mix = cv + 131072;          // 8192
        float* c_mix = h_mix + 8192;         // 8192
        float* hml   = c_mix + 8192;         // 8192
        float* gates = hml + 8192;           // 524288
        float* zbuf  = gates + 524288;       // 131072
        float* atbuf = zbuf + 131072;        // 16384
        float* pls   = atbuf + 16384;        // 4*262144
        float* phi   = pls + 4*262144;       // 3*1966080
        float* Gring = phi + (size_t)3*1966080; // 2*786432
        float* Lring = Gring + 2*786432;     // 2*1081344

        hipMemsetAsync(ws, 0, (size_t)286720 * sizeof(float), stream);

        #define LAUNCH_P(tt) k_P<<<384, 256, 0, stream>>>( \
            hv, cv, gates, pls, W_qkv, W_out, zbuf, atbuf, phi, Gring, Lring, \
            hml, h_mix, w_p, b_p, out, (tt))
        #define LAUNCH_Q(tt) k_Q<<<512, 256, 0, stream>>>( \
            zbuf, atbuf, W_psi, b_psi, phi, x, hv, \
            W_j, W_i, W_f, W_o, U_j, U_i, U_f, U_o, B_j, B_i, B_f, B_o, gates, \
            h_mix, c_mix, hml, \
            u_j, u_i, u_f, u_o, w_j, w_i, w_f, w_o, b_j, b_i, b_f, b_o, (tt))

        // prologue: prime the var-chain 2 steps ahead
        LAUNCH_Q(-3);   // front(0)
        LAUNCH_P(-2);   // attn(0)
        LAUNCH_Q(-2);   // front(1)
        LAUNCH_P(-1);   // attn(1)
        LAUNCH_Q(-1);   // front(2)

        for (int t = 0; t <= 47; ++t) {
            LAUNCH_P(t);
            if (t < 47) LAUNCH_Q(t);
        }
        #undef LAUNCH_P
        #undef LAUNCH_Q
    } else {
        // ================= fallback: round-8 path =================
        float* h_var = ws;                       // 131072
        float* c_var = h_var + 131072;           // 131072
        float* h_mix = c_var + 131072;           // 8192
        float* c_mix = h_mix + 8192;             // 8192
        float* hml   = c_mix + 8192;             // 8192
        float* gates = hml + 8192;               // 524288
        float* phi   = gates + 524288;           // 2*PHIBUF
        float* zbuf  = phi + 3932160;            // 131072
        float* atbuf = zbuf + 131072;            // 16384
        float* Gw    = atbuf + 16384;            // 786432
        float* pls   = Gw + 786432;              // 1048576
        float* ybuf  = pls + 1048576;            // 8192

        hipMemsetAsync(ws, 0, (size_t)278528 * sizeof(float), stream);

        k_Y8<<<512, 256, 0, stream>>>(
            zbuf, atbuf, W_psi, b_psi, phi, x, h_var,
            W_j, W_i, W_f, W_o, U_j, U_i, U_f, U_o, B_j, B_i, B_f, B_o, gates,
            Gw, hml, h_mix, w_p, b_p, ybuf, out, -1, 0, -1);

        for (int t = 0; t < T_ - 1; t++) {
            k_X8<<<448, 256, 0, stream>>>(
                h_var, c_var, gates, pls, W_qkv, W_out, zbuf, atbuf,
                phi, Gw, x, h_mix, c_mix, hml,
                u_j, u_i, u_f, u_o, w_j, w_i, w_f, w_o, b_j, b_i, b_f, b_o,
                ybuf, out, t, t - 1, t - 1, t - 2);
            k_Y8<<<512, 256, 0, stream>>>(
                zbuf, atbuf, W_psi, b_psi, phi, x, h_var,
                W_j, W_i, W_f, W_o, U_j, U_i, U_f, U_o, B_j, B_i, B_f, B_o, gates,
                Gw, hml, h_mix, w_p, b_p, ybuf, out, t, t + 1, t - 1);
        }
        k_X8<<<448, 256, 0, stream>>>(
            h_var, c_var, gates, pls, W_qkv, W_out, zbuf, atbuf,
            phi, Gw, x, h_mix, c_mix, hml,
            u_j, u_i, u_f, u_o, w_j, w_i, w_f, w_o, b_j, b_i, b_f, b_o,
            ybuf, out, -1, T_ - 2, T_ - 2, T_ - 3);
        k_Y8<<<512, 256, 0, stream>>>(
            zbuf, atbuf, W_psi, b_psi, phi, x, h_var,
            W_j, W_i, W_f, W_o, U_j, U_i, U_f, U_o, B_j, B_i, B_f, B_o, gates,
            Gw, hml, h_mix, w_p, b_p, ybuf, out, -1, -1, T_ - 2);
        k_X8<<<448, 256, 0, stream>>>(
            h_var, c_var, gates, pls, W_qkv, W_out, zbuf, atbuf,
            phi, Gw, x, h_mix, c_mix, hml,
            u_j, u_i, u_f, u_o, w_j, w_i, w_f, w_o, b_j, b_i, b_f, b_o,
            ybuf, out, -1, -1, -1, T_ - 2);
    }
}

// Round 13
// 3166.821 us; speedup vs baseline: 1.2122x; 1.2122x over previous
//
#include <hip/hip_runtime.h>
#include <hip/hip_bf16.h>
#include <math.h>

#define B_ 64
#define T_ 48
#define D_ 16
#define H_ 128
#define NU_ 128
#define LAM_ 0.01f
#define THR_ 0.01f

// output offsets (floats)
#define NSTEP_OUT 44
#define OFF_A (B_*NSTEP_OUT)
#define OFF_B (OFF_A + NSTEP_OUT*B_*D_)
#define OFF_G (OFF_B + NSTEP_OUT*B_*D_)

#define PHI_ROWS 240
#define PHI_STR  (PHI_ROWS*H_)                  // 30720
#define PHIBUF   (B_*PHI_STR)                   // 1966080
#define GW_STR   12288                          // packed 3 x 64x64 lower tiles
#define GBUF     (B_*GW_STR)                    // 786432
#define L_STR    16896                          // 128 cols x 132 rows (row 128 = dinv)
#define LBUF     (B_*L_STR)                     // 1081344
#define PLS_STR  4096
#define PLSBUF   (B_*PLS_STR)                   // 262144

#define QKS 388
#define SCS 264

__device__ __forceinline__ float sigm(float v) { return 1.0f / (1.0f + expf(-v)); }
__device__ __forceinline__ float dot4(float4 a, float4 b) {
    return a.x*b.x + a.y*b.y + a.z*b.z + a.w*b.w;
}
__device__ __forceinline__ float rdlane(float v, int l) {
    return __uint_as_float(__builtin_amdgcn_readlane(__float_as_uint(v), l));
}

// ===========================================================================
// PIPELINED PATH
// k_P(t): [0,64) attn(t+2) | [64,256) gram(t+1) | [256,320) trisolve+epi(t-1)
// k_Q(t): [0,128) factor(t / t+1, even t only) | [128,448) psi(t+2)
//         [448,576) front(t+3) | [576,640) mix(t)
// ===========================================================================

__global__ __launch_bounds__(256) void k_P(
    float* __restrict__ hv, float* __restrict__ cv,
    const float* __restrict__ gates, float* __restrict__ pls,
    const float* __restrict__ Wqkv, const float* __restrict__ Wout,
    float* __restrict__ z, float* __restrict__ at_g,
    const float* __restrict__ phi, float* __restrict__ Gring,
    const float* __restrict__ Lring,
    const float* __restrict__ hml, float* __restrict__ h_mix,
    const float* __restrict__ w_p, const float* __restrict__ b_p,
    float* __restrict__ out, int t)
{
    __shared__ __align__(16) float smem[12416];
    const int tid = threadIdx.x;
    const int bx = blockIdx.x;

    if (bx < 64) {
        // ================= attention for step ta = t+2 =================
        const int ta = t + 2;
        if (ta < 0 || ta > T_ - 2) return;
        const int b = bx;
        const int BDH = B_*D_*H_;
        float* hs = smem;            // [2048]
        float* qk = smem + 2048;     // [16][QKS]
        float* sc = smem + 8256;     // [8][SCS]
        float* cx = smem + 10368;    // [2048]

        float* plsb = pls + ((size_t)(ta&3))*PLSBUF + (size_t)b*PLS_STR;
        const float4* g0 = (const float4*)(gates + b*2048);
        const float4* g1 = (const float4*)(gates + BDH + b*2048);
        const float4* g2 = (const float4*)(gates + 2*BDH + b*2048);
        const float4* g3 = (const float4*)(gates + 3*BDH + b*2048);
        float4* cv4 = (float4*)(cv + b*2048);
        float4* hv4 = (float4*)(hv + b*2048);
        float4* pl0 = (float4*)plsb;
        float4* pl1 = (float4*)(plsb + 16*H_);
        #pragma unroll
        for (int i = 0; i < 2; ++i) {
            int e4 = i*256 + tid;
            float4 jv = g0[e4], iv = g1[e4], fv = g2[e4], ov = g3[e4];
            float4 c = cv4[e4], ho = hv4[e4];
            float4 cn, hn, dl;
            cn.x = c.x*fv.x + iv.x*jv.x; hn.x = ov.x*tanhf(cn.x); dl.x = hn.x - ho.x;
            cn.y = c.y*fv.y + iv.y*jv.y; hn.y = ov.y*tanhf(cn.y); dl.y = hn.y - ho.y;
            cn.z = c.z*fv.z + iv.z*jv.z; hn.z = ov.z*tanhf(cn.z); dl.z = hn.z - ho.z;
            cn.w = c.w*fv.w + iv.w*jv.w; hn.w = ov.w*tanhf(cn.w); dl.w = hn.w - ho.w;
            cv4[e4] = cn; hv4[e4] = hn;
            ((float4*)hs)[e4] = hn;
            pl0[e4] = ho;
            pl1[e4] = dl;
        }
        __syncthreads();

        // qkv = h_var @ Wqkv^T
        {
            const int half = tid >> 7, mt = tid & 127;
            const float4* w0 = (const float4*)(Wqkv + (size_t)(mt*3 + 0)*H_);
            const float4* w1 = (const float4*)(Wqkv + (size_t)(mt*3 + 1)*H_);
            const float4* w2 = (const float4*)(Wqkv + (size_t)(mt*3 + 2)*H_);
            float acc[3][8] = {};
            for (int i4 = 0; i4 < 32; i4++) {
                float4 wa = w0[i4], wb = w1[i4], wc = w2[i4];
                #pragma unroll
                for (int rr = 0; rr < 8; rr++) {
                    float4 h4 = *(const float4*)&hs[(half*8 + rr)*128 + i4*4];
                    acc[0][rr] += dot4(wa, h4);
                    acc[1][rr] += dot4(wb, h4);
                    acc[2][rr] += dot4(wc, h4);
                }
            }
            #pragma unroll
            for (int q = 0; q < 3; q++)
                #pragma unroll
                for (int rr = 0; rr < 8; rr++)
                    qk[(half*8 + rr)*QKS + mt*3 + q] = acc[q][rr];
        }
        __syncthreads();

        // scores
        for (int e = tid; e < 2048; e += 256) {
            int hh2 = e >> 8, qd = (e >> 4) & 15, kd = e & 15;
            float s = 0.f;
            #pragma unroll
            for (int e4 = 0; e4 < 4; e4++)
                s += dot4(*(const float4*)&qk[qd*QKS + hh2*16 + e4*4],
                          *(const float4*)&qk[kd*QKS + 128 + hh2*16 + e4*4]);
            sc[hh2*SCS + qd*16 + kd] = s * 0.25f;
        }
        __syncthreads();

        // softmax + threshold
        if (tid < 128) {
            int hh2 = tid >> 4, qd = tid & 15;
            float mx = -1e30f;
            #pragma unroll
            for (int kd = 0; kd < 16; kd++) mx = fmaxf(mx, sc[hh2*SCS + qd*16 + kd]);
            float ex[16]; float s = 0.f;
            #pragma unroll
            for (int kd = 0; kd < 16; kd++) { ex[kd] = expf(sc[hh2*SCS + qd*16 + kd] - mx); s += ex[kd]; }
            float inv = 1.0f / s;
            #pragma unroll
            for (int kd = 0; kd < 16; kd++) {
                float a = ex[kd]*inv;
                sc[hh2*SCS + qd*16 + kd] = (a >= THR_) ? a : 0.0f;
            }
        }
        __syncthreads();

        // a_t mean over heads
        {
            int qd = tid >> 4, kd = tid & 15;
            float s = 0.f;
            #pragma unroll
            for (int hh2 = 0; hh2 < 8; hh2++) s += sc[hh2*SCS + qd*16 + kd];
            at_g[b*256 + qd*16 + kd] = s * 0.125f;
        }

        // ctx
        for (int e = tid; e < 2048; e += 256) {
            int qd = e >> 7, c = e & 127, hh2 = c >> 4, ee = c & 15;
            float s = 0.f;
            #pragma unroll
            for (int kd = 0; kd < 16; kd++) s += sc[hh2*SCS + qd*16 + kd] * qk[kd*QKS + 256 + hh2*16 + ee];
            cx[qd*128 + c] = s;
        }
        __syncthreads();

        // z = ctx @ Wout^T
        {
            int h = tid & 127, half = tid >> 7;
            const float4* wr = (const float4*)(Wout + (size_t)h*H_);
            float acc[8] = {};
            for (int i4 = 0; i4 < 32; i4++) {
                float4 w4 = wr[i4];
                #pragma unroll
                for (int r = 0; r < 8; r++)
                    acc[r] += dot4(w4, *(const float4*)&cx[(half*8 + r)*128 + i4*4]);
            }
            #pragma unroll
            for (int r = 0; r < 8; r++) z[b*2048 + (half*8 + r)*H_ + h] = acc[r];
        }
    } else if (bx < 256) {
        // ================= gram for step tg = t+1 (reg-prefetched staging) ==
        const int tg = t + 1;
        if (tg < 3 || tg > T_ - 2) return;
        const int tile = (bx - 64) >> 6, b = (bx - 64) & 63;
        const int r0 = (tile >= 1) ? 64 : 0;
        const int c0 = (tile == 2) ? 64 : 0;
        const bool diag = (r0 == c0);
        float* prt = smem;           // [16][64]
        float* pct = smem + 1024;    // [16][64]
        const float* pb   = phi + ((size_t)(tg%3))*PHIBUF + (size_t)b*PHI_STR;
        const float* plsb = pls + ((size_t)(tg&3))*PLSBUF + (size_t)b*PLS_STR;
        const int tr = tid >> 4, tc = tid & 15;
        const int kk = tid >> 4, rr4 = (tid & 15) << 2;
        float acc[4][4] = {};
        float4 vr, vc;

        // preload chunk 0
        {
            const float* src = (kk < 32) ? (plsb + (size_t)kk*H_) : (pb + (size_t)(kk - 32)*H_);
            vr = *(const float4*)&src[r0 + rr4];
            if (!diag) vc = *(const float4*)&src[c0 + rr4];
        }
        for (int kt = 0; kt < 17; kt++) {
            *(float4*)&prt[kk*64 + rr4] = vr;
            if (!diag) *(float4*)&pct[kk*64 + rr4] = vc;
            __syncthreads();
            if (kt < 16) {
                int krow = (kt + 1)*16 + kk;
                const float* src = (krow < 32) ? (plsb + (size_t)krow*H_)
                                               : (pb + (size_t)(krow - 32)*H_);
                vr = *(const float4*)&src[r0 + rr4];
                if (!diag) vc = *(const float4*)&src[c0 + rr4];
            }
            const float* pcb = diag ? prt : pct;
            #pragma unroll
            for (int k2 = 0; k2 < 16; k2++) {
                float4 a4 = *(const float4*)&prt[k2*64 + tr*4];
                float4 b4 = *(const float4*)&pcb[k2*64 + tc*4];
                float av[4] = {a4.x, a4.y, a4.z, a4.w};
                float bv[4] = {b4.x, b4.y, b4.z, b4.w};
                #pragma unroll
                for (int i = 0; i < 4; i++)
                    #pragma unroll
                    for (int j = 0; j < 4; j++)
                        acc[i][j] += av[i]*bv[j];
            }
            __syncthreads();
        }
        float* Gt = Gring + ((size_t)(tg&1))*GBUF + (size_t)b*GW_STR + (size_t)tile*4096;
        #pragma unroll
        for (int i = 0; i < 4; i++) {
            int lr = tr*4 + i;
            float v[4];
            #pragma unroll
            for (int j = 0; j < 4; j++) {
                int lc = tc*4 + j;
                v[j] = acc[i][j] + ((diag && lr == lc) ? LAM_ : 0.0f);
            }
            float4 o; o.x = v[0]; o.y = v[1]; o.z = v[2]; o.w = v[3];
            *(float4*)&Gt[lr*64 + tc*4] = o;
        }
    } else {
        // ======= trisolve (L streamed from global) + finalize + epi, tv = t-1
        const int tv = t - 1;
        if (tv < 0 || tv > T_ - 2) return;
        const int b = bx - 256;
        if (tv < 3) {
            if (tid < 128) h_mix[b*128 + tid] = hml[b*128 + tid];
            return;
        }
        float* ys = smem;            // [128] — y, then x in place
        const float* Lb = Lring + ((size_t)(tv&1))*LBUF + (size_t)b*L_STR;

        if (tid < 64) {
            __builtin_amdgcn_s_setprio(1);
            const int lane = tid;
            float hm0 = hml[b*128 + lane];
            float hm1 = hml[b*128 + lane + 64];
            float dv0 = Lb[lane*132 + 128];
            float dv1 = Lb[(lane+64)*132 + 128];
            float acc0 = hm0, acc1 = hm1;

            // ---- forward, cols 0..63 (rows lane, lane+64), 16-col prefetch
            {
                float c0[16], c1[16], n0[16], n1[16];
                #pragma unroll
                for (int k = 0; k < 16; ++k) {
                    c0[k] = Lb[k*132 + lane];
                    c1[k] = Lb[k*132 + lane + 64];
                }
                for (int g = 0; g < 4; ++g) {
                    if (g < 3) {
                        #pragma unroll
                        for (int k = 0; k < 16; ++k) {
                            n0[k] = Lb[(16*(g+1)+k)*132 + lane];
                            n1[k] = Lb[(16*(g+1)+k)*132 + lane + 64];
                        }
                    }
                    const int s = 16*g;
                    #pragma unroll
                    for (int k = 0; k < 16; ++k) {
                        int j = s + k;
                        float yj = rdlane(acc0 * dv0, j);
                        if (lane > j) acc0 -= c0[k]*yj;
                        else if (lane == j) acc0 = yj;
                        acc1 -= c1[k]*yj;
                    }
                    #pragma unroll
                    for (int k = 0; k < 16; ++k) { c0[k] = n0[k]; c1[k] = n1[k]; }
                }
            }
            // ---- forward, cols 64..127 (row lane+64 only)
            {
                float c1[16], n1[16];
                #pragma unroll
                for (int k = 0; k < 16; ++k) c1[k] = Lb[(64+k)*132 + lane + 64];
                for (int g = 0; g < 4; ++g) {
                    if (g < 3) {
                        #pragma unroll
                        for (int k = 0; k < 16; ++k)
                            n1[k] = Lb[(64+16*(g+1)+k)*132 + lane + 64];
                    }
                    #pragma unroll
                    for (int k = 0; k < 16; ++k) {
                        int j = 16*g + k;              // local col (actual 64+j)
                        float yj = rdlane(acc1 * dv1, j);
                        if (lane > j) acc1 -= c1[k]*yj;
                        else if (lane == j) acc1 = yj;
                    }
                    #pragma unroll
                    for (int k = 0; k < 16; ++k) c1[k] = n1[k];
                }
            }
            ys[lane] = acc0;
            ys[lane + 64] = acc1;

            // ---- backward: L^T x = y (per-lane-contiguous float4 reads)
            for (int p = 7; p >= 0; --p) {
                const int s = p*16;
                float br = 0.f, minv = 0.f;
                float lc[16];
                if (lane < 16) {
                    br = ys[s + lane];
                    minv = Lb[(s+lane)*132 + 128];
                    #pragma unroll
                    for (int k4 = 0; k4 < 4; ++k4) {
                        float4 f4 = *(const float4*)&Lb[(s+lane)*132 + s + k4*4];
                        lc[k4*4+0]=f4.x; lc[k4*4+1]=f4.y; lc[k4*4+2]=f4.z; lc[k4*4+3]=f4.w;
                    }
                } else {
                    #pragma unroll
                    for (int k = 0; k < 16; ++k) lc[k] = 0.f;
                }
                float xk[16];
                #pragma unroll
                for (int j = 15; j >= 0; --j) {
                    if (lane == j) br *= minv;
                    float xj = rdlane(br, j);
                    if (lane < j) br -= lc[j]*xj;
                    xk[j] = xj;
                }
                if (lane < 16) ys[s + lane] = br;
                for (int i = lane; i < s; i += 64) {
                    float a = ys[i];
                    #pragma unroll
                    for (int k4 = 0; k4 < 4; ++k4) {
                        float4 f4 = *(const float4*)&Lb[i*132 + s + k4*4];
                        a -= f4.x*xk[k4*4] + f4.y*xk[k4*4+1] + f4.z*xk[k4*4+2] + f4.w*xk[k4*4+3];
                    }
                    ys[i] = a;
                }
            }

            // ---- finalize
            float y0 = ys[lane], y1 = ys[lane + 64];
            float hh0 = hm0 - LAM_*y0, hh1 = hm1 - LAM_*y1;
            h_mix[b*128 + lane]      = hh0;
            h_mix[b*128 + lane + 64] = hh1;
            float pw = hh0 * w_p[lane] + hh1 * w_p[lane + 64];
            for (int off = 32; off; off >>= 1) pw += __shfl_down(pw, off);
            if (lane == 0) out[b*NSTEP_OUT + (tv - 3)] = pw + b_p[0];
            __builtin_amdgcn_s_setprio(0);
        }
        __syncthreads();

        // theta epilogue (all 256 threads)
        {
            const int ts = tv - 3;
            const float* plsb = pls + ((size_t)(tv&3))*PLSBUF + (size_t)b*PLS_STR;
            const float* phb  = phi + ((size_t)(tv%3))*PHIBUF + (size_t)b*PHI_STR;
            const float4* y4  = (const float4*)ys;
            for (int k = tid; k < 272; k += 256) {
                const float* rowp = (k < 32) ? plsb + (size_t)k*H_
                                             : phb + (size_t)(k - 32)*H_;
                const float4* r4 = (const float4*)rowp;
                float th = 0.f;
                #pragma unroll
                for (int i4 = 0; i4 < 32; i4++) th += dot4(r4[i4], y4[i4]);
                if (k < 16)
                    out[OFF_A + ts*(B_*D_) + b*D_ + k] = th;
                else if (k < 32)
                    out[OFF_B + ts*(B_*D_) + b*D_ + (k - 16)] = th;
                else {
                    int p = k - 32, ip = p/15, jj = p%15, jp = jj + (jj >= ip ? 1 : 0);
                    out[OFF_G + ts*(B_*D_*D_) + b*(D_*D_) + ip*D_ + jp] = th;
                }
            }
            if (tid < D_)
                out[OFF_G + ts*(B_*D_*D_) + b*(D_*D_) + tid*D_ + tid] = 0.0f;
        }
    }
}

__global__ __launch_bounds__(256) void k_Q(
    const float* __restrict__ z, const float* __restrict__ at,
    const float* __restrict__ Wpsi, const float* __restrict__ bpsi,
    float* __restrict__ phi,
    const float* __restrict__ x, const float* __restrict__ hv,
    const float* __restrict__ Wj, const float* __restrict__ Wi, const float* __restrict__ Wf, const float* __restrict__ Wo,
    const float* __restrict__ Uj, const float* __restrict__ Ui, const float* __restrict__ Uf, const float* __restrict__ Uo,
    const float* __restrict__ Bj, const float* __restrict__ Bi, const float* __restrict__ Bf, const float* __restrict__ Bo,
    float* __restrict__ gates,
    const float* __restrict__ Gring, float* __restrict__ Lring,
    const float* __restrict__ h_mix, float* __restrict__ c_mix, float* __restrict__ hml,
    const float* __restrict__ uj, const float* __restrict__ ui, const float* __restrict__ uf, const float* __restrict__ uo,
    const float* __restrict__ wj, const float* __restrict__ wi, const float* __restrict__ wf, const float* __restrict__ wo,
    const float* __restrict__ bj, const float* __restrict__ bi, const float* __restrict__ bf_, const float* __restrict__ bo,
    int t)
{
    __shared__ __align__(16) float smem[16896];
    const int tid = threadIdx.x;
    const int bx = blockIdx.x;

    if (bx < 128) {
        // ================= factor (Cholesky only) for tf =================
        const int tf = t + (bx >> 6);
        if ((t & 1) || tf < 3 || tf > T_ - 2) return;
        const int b = bx & 63;
        float* Ac = smem;   // col-major [col*132 + row]; row 128 = dinv

        const int R = tid >> 4, C = tid & 15;
        const bool lower = (C <= R);

        // load packed lower G into registers
        float g[8][8] = {};
        if (lower) {
            const int tsel = (C >= 8) ? 2 : ((R >= 8) ? 1 : 0);
            const float* Gt = Gring + ((size_t)(tf&1))*GBUF + (size_t)b*GW_STR + (size_t)tsel*4096;
            const int lcb = C*8 - ((C >= 8) ? 64 : 0);
            #pragma unroll
            for (int r = 0; r < 8; ++r) {
                const int lr = R*8 + r - ((R >= 8) ? 64 : 0);
                float4 lo = *(const float4*)(Gt + lr*64 + lcb);
                float4 hi = *(const float4*)(Gt + lr*64 + lcb + 4);
                g[r][0]=lo.x; g[r][1]=lo.y; g[r][2]=lo.z; g[r][3]=lo.w;
                g[r][4]=hi.x; g[r][5]=hi.y; g[r][6]=hi.z; g[r][7]=hi.w;
            }
        }

        // blocked Cholesky
        for (int p = 0; p < 8; ++p) {
            const int s = p*16;
            if ((C >> 1) == p && R >= 2*p) {
                #pragma unroll
                for (int c = 0; c < 8; ++c) {
                    float4 lo = {g[0][c], g[1][c], g[2][c], g[3][c]};
                    float4 hi = {g[4][c], g[5][c], g[6][c], g[7][c]};
                    *(float4*)&Ac[(C*8 + c)*132 + R*8]     = lo;
                    *(float4*)&Ac[(C*8 + c)*132 + R*8 + 4] = hi;
                }
            }
            __syncthreads();
            if (tid < 64) {
                const int lane = tid;
                const int r0 = s + lane, r1 = r0 + 64;
                const bool v0 = r0 < 128, v1 = r1 < 128;
                float a0[16], a1[16];
                #pragma unroll
                for (int k = 0; k < 16; ++k) {
                    a0[k] = v0 ? Ac[(s+k)*132 + r0] : 0.f;
                    a1[k] = v1 ? Ac[(s+k)*132 + r1] : 0.f;
                }
                float myinv = 0.f;
                #pragma unroll
                for (int j = 0; j < 16; ++j) {
                    float piv = rdlane(a0[j], j);
                    float inv = rsqrtf(piv);
                    float dsq = piv * inv;
                    if (lane == j) myinv = inv;
                    a0[j] = (lane == j) ? dsq : a0[j]*inv;
                    a1[j] *= inv;
                    #pragma unroll
                    for (int c = j+1; c < 16; ++c) {
                        float Lcj = rdlane(a0[j], c);
                        a0[c] -= a0[j]*Lcj;
                        a1[c] -= a1[j]*Lcj;
                    }
                }
                if (lane < 16) Ac[(s+lane)*132 + 128] = myinv;   // dinv in pad row
                #pragma unroll
                for (int k = 0; k < 16; ++k) {
                    if (v0) Ac[(s+k)*132 + r0] = a0[k];
                    if (v1) Ac[(s+k)*132 + r1] = a1[k];
                }
            }
            __syncthreads();
            // trailing rank-16 update in registers (prefetched)
            if (lower && C >= 2*(p+1)) {
                const float* colp = &Ac[s*132];
                float4 r04 = *(const float4*)&colp[R*8];
                float4 r14 = *(const float4*)&colp[R*8 + 4];
                float4 c04 = *(const float4*)&colp[C*8];
                float4 c14 = *(const float4*)&colp[C*8 + 4];
                #pragma unroll
                for (int k = 0; k < 16; ++k) {
                    float lr[8] = {r04.x,r04.y,r04.z,r04.w,r14.x,r14.y,r14.z,r14.w};
                    float lc[8] = {c04.x,c04.y,c04.z,c04.w,c14.x,c14.y,c14.z,c14.w};
                    if (k < 15) {
                        const float* coln = &Ac[(s+k+1)*132];
                        r04 = *(const float4*)&coln[R*8];
                        r14 = *(const float4*)&coln[R*8 + 4];
                        c04 = *(const float4*)&coln[C*8];
                        c14 = *(const float4*)&coln[C*8 + 4];
                    }
                    #pragma unroll
                    for (int r = 0; r < 8; ++r)
                        #pragma unroll
                        for (int c = 0; c < 8; ++c)
                            g[r][c] -= lr[r]*lc[c];
                }
            }
        }
        __syncthreads();
        // store L to global
        {
            float* Lb = Lring + ((size_t)(tf&1))*LBUF + (size_t)b*L_STR;
            const float4* s4 = (const float4*)Ac;
            float4* d4 = (float4*)Lb;
            for (int e = tid; e < 4224; e += 256) d4[e] = s4[e];
        }
    } else if (bx < 448) {
        // ================= psi for tp = t+2 (6x4 register-blocked) =========
        const int tp = t + 2;
        if (tp < 3 || tp > T_ - 2) return;
        const int pc = (bx - 128) >> 6, b = (bx - 128) & 63;
        const int p0 = pc * 48;
        float* zs = smem;           // [2048]
        float* pr = smem + 2048;    // [48][128]

        {
            const float4* zsrc = (const float4*)(z + b*2048);
            #pragma unroll
            for (int i = 0; i < 2; ++i) ((float4*)zs)[i*256 + tid] = zsrc[i*256 + tid];
        }
        __syncthreads();
        for (int e = tid; e < 48*128; e += 256) {
            int pp = e >> 7, c = e & 127;
            int p = p0 + pp, ip = p/15, jj2 = p%15, jp = jj2 + (jj2 >= ip ? 1 : 0);
            pr[pp*128 + c] = zs[ip*128 + c] * zs[jp*128 + c];
        }
        __syncthreads();

        const int hg = tid & 31, pg = tid >> 5;
        const int h0 = hg*4, pp0 = pg*6;
        const float4* w0 = (const float4*)(Wpsi + (size_t)(h0+0)*H_);
        const float4* w1 = (const float4*)(Wpsi + (size_t)(h0+1)*H_);
        const float4* w2 = (const float4*)(Wpsi + (size_t)(h0+2)*H_);
        const float4* w3 = (const float4*)(Wpsi + (size_t)(h0+3)*H_);
        float acc[6][4] = {};
        for (int i4 = 0; i4 < 32; i4++) {
            float4 wa = w0[i4], wb = w1[i4], wc = w2[i4], wd = w3[i4];
            #pragma unroll
            for (int r = 0; r < 6; r++) {
                float4 p4 = *(const float4*)&pr[(pp0 + r)*128 + i4*4];
                acc[r][0] += dot4(wa, p4);
                acc[r][1] += dot4(wb, p4);
                acc[r][2] += dot4(wc, p4);
                acc[r][3] += dot4(wd, p4);
            }
        }
        float4 bb = *(const float4*)&bpsi[h0];
        float* phb = phi + ((size_t)(tp%3))*PHIBUF + (size_t)b*PHI_STR;
        #pragma unroll
        for (int r = 0; r < 6; r++) {
            int pp = pp0 + r, p = p0 + pp;
            int ip = p/15, jj2 = p%15, jp = jj2 + (jj2 >= ip ? 1 : 0);
            float wat = at[b*256 + ip*16 + jp];
            float4 o;
            o.x = tanhf(acc[r][0] + bb.x) * wat;
            o.y = tanhf(acc[r][1] + bb.y) * wat;
            o.z = tanhf(acc[r][2] + bb.z) * wat;
            o.w = tanhf(acc[r][3] + bb.w) * wat;
            *(float4*)&phb[(size_t)p*H_ + h0] = o;
        }
    } else if (bx < 576) {
        // ================= front: var-gate GEMM for tn = t+3 ===============
        const int tn = t + 3;
        if (tn < 0 || tn > T_ - 2) return;
        float* hsT = smem;            // [128][68]
        float* Ws  = smem + 8704;     // [64][64]
        const int fbx = bx - 448;
        const int kh = fbx & 1, g = (fbx >> 1) & 3, d = fbx >> 3;
        const int k0 = kh * 64;
        const float* W  = (g==0?Wj:(g==1?Wi:(g==2?Wf:Wo))) + (size_t)d*H_*H_;
        const float* U  = (g==0?Uj:(g==1?Ui:(g==2?Uf:Uo))) + d*H_;
        const float* Bp = (g==0?Bj:(g==1?Bi:(g==2?Bf:Bo))) + d*H_;

        for (int e = tid; e < 64*128; e += 256) {
            int b2 = e >> 7, h2 = e & 127;
            hsT[h2*68 + b2] = hv[(b2*D_ + d)*H_ + h2];
        }
        const int tb = tid >> 4, tk = tid & 15;
        float acc[4][4] = {};

        for (int hc = 0; hc < 2; hc++) {
            __syncthreads();
            for (int e = tid; e < 64*64; e += 256) {
                int h2 = e >> 6, kk = e & 63;
                Ws[h2*64 + kk] = W[(hc*64 + h2)*H_ + k0 + kk];
            }
            __syncthreads();
            for (int h2 = 0; h2 < 64; h2++) {
                float4 hb = *(const float4*)&hsT[(hc*64 + h2)*68 + tb*4];
                float4 wk = *(const float4*)&Ws[h2*64 + tk*4];
                float hbv[4] = {hb.x, hb.y, hb.z, hb.w};
                float wkv[4] = {wk.x, wk.y, wk.z, wk.w};
                #pragma unroll
                for (int a2 = 0; a2 < 4; a2++)
                    #pragma unroll
                    for (int c2 = 0; c2 < 4; c2++)
                        acc[a2][c2] += hbv[a2] * wkv[c2];
            }
        }

        float u4[4], bp4[4];
        #pragma unroll
        for (int c2 = 0; c2 < 4; c2++) { u4[c2] = U[k0 + tk*4 + c2]; bp4[c2] = Bp[k0 + tk*4 + c2]; }

        #pragma unroll
        for (int a2 = 0; a2 < 4; a2++) {
            int b2 = tb*4 + a2;
            float xv = x[(b2*T_ + tn)*D_ + d];
            float4 o;
            float pre[4];
            #pragma unroll
            for (int c2 = 0; c2 < 4; c2++) pre[c2] = acc[a2][c2] + xv*u4[c2] + bp4[c2];
            if (g == 0) { o.x = tanhf(pre[0]); o.y = tanhf(pre[1]); o.z = tanhf(pre[2]); o.w = tanhf(pre[3]); }
            else        { o.x = sigm(pre[0]);  o.y = sigm(pre[1]);  o.z = sigm(pre[2]);  o.w = sigm(pre[3]); }
            *(float4*)&gates[(size_t)g*(B_*D_*H_) + (b2*D_ + d)*H_ + k0 + tk*4] = o;
        }
    } else {
        // ================= mix-LSTM for tm = t =================
        const int tm = t;
        if (tm < 0 || tm > T_ - 2) return;
        const int b = bx - 576;
        float* xs  = smem;
        float* hs2 = smem + 16;
        float* gj  = smem + 144;
        float* gi  = smem + 272;
        float* gf  = smem + 400;
        float* go  = smem + 528;
        const int n = tid & 127, gg = tid >> 7;
        if (tid < 16)  xs[tid]  = x[(b*T_ + tm)*D_ + tid];
        if (tid < 128) hs2[tid] = h_mix[b*NU_ + tid];
        __syncthreads();

        const float* uA = gg ? uf : uj;
        const float* uB = gg ? uo : ui;
        const float* wA = gg ? wf : wj;
        const float* wB = gg ? wo : wi;
        float accA = gg ? bf_[n] : bj[n];
        float accB = gg ? bo[n]  : bi[n];
        #pragma unroll
        for (int d2 = 0; d2 < 16; ++d2) {
            float xv = xs[d2];
            accA += xv * uA[d2*NU_ + n];
            accB += xv * uB[d2*NU_ + n];
        }
        for (int m = 0; m < 128; ++m) {
            float hvv = hs2[m];
            accA += hvv * wA[m*NU_ + n];
            accB += hvv * wB[m*NU_ + n];
        }
        if (gg == 0) { gj[n] = tanhf(accA); gi[n] = sigm(accB); }
        else         { gf[n] = sigm(accA);  go[n] = sigm(accB); }
        __syncthreads();
        if (tid < 128) {
            float cn = gf[tid]*c_mix[b*NU_ + tid] + gi[tid]*gj[tid];
            c_mix[b*NU_ + tid] = cn;
            hml[b*NU_ + tid]   = go[tid]*tanhf(cn);
        }
    }
}

// ===========================================================================
// FALLBACK PATH (round-8 code, used when ws is too small)
// ===========================================================================

__global__ __launch_bounds__(256) void k_X8(
    float* __restrict__ hv, float* __restrict__ cv,
    const float* __restrict__ gates, float* __restrict__ pls,
    const float* __restrict__ Wqkv, const float* __restrict__ Wout,
    float* __restrict__ z, float* __restrict__ at_g,
    const float* __restrict__ phi, float* __restrict__ Gw,
    const float* __restrict__ x, const float* __restrict__ h_mix,
    float* __restrict__ c_mix, float* __restrict__ hml,
    const float* __restrict__ uj, const float* __restrict__ ui, const float* __restrict__ uf, const float* __restrict__ uo,
    const float* __restrict__ wj, const float* __restrict__ wi, const float* __restrict__ wf, const float* __restrict__ wo,
    const float* __restrict__ bj, const float* __restrict__ bi, const float* __restrict__ bf_, const float* __restrict__ bo,
    const float* __restrict__ ybuf, float* __restrict__ out,
    int ta, int tg, int tm, int te)
{
    __shared__ __align__(16) float smem[12416];
    const int tid = threadIdx.x;
    const int bx = blockIdx.x;

    if (bx < 64) {
        if (ta < 0) return;
        const int b = bx;
        const int BDH = B_*D_*H_;
        float* hs = smem;
        float* qk = smem + 2048;
        float* sc = smem + 8256;
        float* cx = smem + 10368;

        float* plsb = pls + ((size_t)(ta&3)*B_ + b)*PLS_STR;
        const float4* g0 = (const float4*)(gates + b*2048);
        const float4* g1 = (const float4*)(gates + BDH + b*2048);
        const float4* g2 = (const float4*)(gates + 2*BDH + b*2048);
        const float4* g3 = (const float4*)(gates + 3*BDH + b*2048);
        float4* cv4 = (float4*)(cv + b*2048);
        float4* hv4 = (float4*)(hv + b*2048);
        float4* pl0 = (float4*)plsb;
        float4* pl1 = (float4*)(plsb + 16*H_);
        #pragma unroll
        for (int i = 0; i < 2; ++i) {
            int e4 = i*256 + tid;
            float4 jv = g0[e4], iv = g1[e4], fv = g2[e4], ov = g3[e4];
            float4 c = cv4[e4], ho = hv4[e4];
            float4 cn, hn, dl;
            cn.x = c.x*fv.x + iv.x*jv.x; hn.x = ov.x*tanhf(cn.x); dl.x = hn.x - ho.x;
            cn.y = c.y*fv.y + iv.y*jv.y; hn.y = ov.y*tanhf(cn.y); dl.y = hn.y - ho.y;
            cn.z = c.z*fv.z + iv.z*jv.z; hn.z = ov.z*tanhf(cn.z); dl.z = hn.z - ho.z;
            cn.w = c.w*fv.w + iv.w*jv.w; hn.w = ov.w*tanhf(cn.w); dl.w = hn.w - ho.w;
            cv4[e4] = cn; hv4[e4] = hn;
            ((float4*)hs)[e4] = hn;
            pl0[e4] = ho;
            pl1[e4] = dl;
        }
        __syncthreads();
        {
            const int half = tid >> 7, mt = tid & 127;
            const float4* w0 = (const float4*)(Wqkv + (size_t)(mt*3 + 0)*H_);
            const float4* w1 = (const float4*)(Wqkv + (size_t)(mt*3 + 1)*H_);
            const float4* w2 = (const float4*)(Wqkv + (size_t)(mt*3 + 2)*H_);
            float acc[3][8] = {};
            for (int i4 = 0; i4 < 32; i4++) {
                float4 wa = w0[i4], wb = w1[i4], wc = w2[i4];
                #pragma unroll
                for (int rr = 0; rr < 8; rr++) {
                    float4 h4 = *(const float4*)&hs[(half*8 + rr)*128 + i4*4];
                    acc[0][rr] += dot4(wa, h4);
                    acc[1][rr] += dot4(wb, h4);
                    acc[2][rr] += dot4(wc, h4);
                }
            }
            #pragma unroll
            for (int q = 0; q < 3; q++)
                #pragma unroll
                for (int rr = 0; rr < 8; rr++)
                    qk[(half*8 + rr)*QKS + mt*3 + q] = acc[q][rr];
        }
        __syncthreads();
        for (int e = tid; e < 2048; e += 256) {
            int hh2 = e >> 8, qd = (e >> 4) & 15, kd = e & 15;
            float s = 0.f;
            #pragma unroll
            for (int e4 = 0; e4 < 4; e4++)
                s += dot4(*(const float4*)&qk[qd*QKS + hh2*16 + e4*4],
                          *(const float4*)&qk[kd*QKS + 128 + hh2*16 + e4*4]);
            sc[hh2*SCS + qd*16 + kd] = s * 0.25f;
        }
        __syncthreads();
        if (tid < 128) {
            int hh2 = tid >> 4, qd = tid & 15;
            float mx = -1e30f;
            #pragma unroll
            for (int kd = 0; kd < 16; kd++) mx = fmaxf(mx, sc[hh2*SCS + qd*16 + kd]);
            float ex[16]; float s = 0.f;
            #pragma unroll
            for (int kd = 0; kd < 16; kd++) { ex[kd] = expf(sc[hh2*SCS + qd*16 + kd] - mx); s += ex[kd]; }
            float inv = 1.0f / s;
            #pragma unroll
            for (int kd = 0; kd < 16; kd++) {
                float a = ex[kd]*inv;
                sc[hh2*SCS + qd*16 + kd] = (a >= THR_) ? a : 0.0f;
            }
        }
        __syncthreads();
        {
            int qd = tid >> 4, kd = tid & 15;
            float s = 0.f;
            #pragma unroll
            for (int hh2 = 0; hh2 < 8; hh2++) s += sc[hh2*SCS + qd*16 + kd];
            at_g[b*256 + qd*16 + kd] = s * 0.125f;
        }
        for (int e = tid; e < 2048; e += 256) {
            int qd = e >> 7, c = e & 127, hh2 = c >> 4, ee = c & 15;
            float s = 0.f;
            #pragma unroll
            for (int kd = 0; kd < 16; kd++) s += sc[hh2*SCS + qd*16 + kd] * qk[kd*QKS + 256 + hh2*16 + ee];
            cx[qd*128 + c] = s;
        }
        __syncthreads();
        {
            int h = tid & 127, half = tid >> 7;
            const float4* wr = (const float4*)(Wout + (size_t)h*H_);
            float acc[8] = {};
            for (int i4 = 0; i4 < 32; i4++) {
                float4 w4 = wr[i4];
                #pragma unroll
                for (int r = 0; r < 8; r++)
                    acc[r] += dot4(w4, *(const float4*)&cx[(half*8 + r)*128 + i4*4]);
            }
            #pragma unroll
            for (int r = 0; r < 8; r++) z[b*2048 + (half*8 + r)*H_ + h] = acc[r];
        }
    } else if (bx < 256) {
        if (tg < 0) return;
        const int tile = (bx - 64) >> 6, b = (bx - 64) & 63;
        const int r0 = (tile >= 1) ? 64 : 0;
        const int c0 = (tile == 2) ? 64 : 0;
        const bool diag = (r0 == c0);
        float* prt = smem;
        float* pct = smem + 1024;
        const float* pb   = phi + (size_t)(tg&1)*PHIBUF + (size_t)b*PHI_STR;
        const float* plsb = pls + ((size_t)(tg&3)*B_ + b)*PLS_STR;
        const int tr = tid >> 4, tc = tid & 15;
        float acc[4][4] = {};
        for (int kt = 0; kt < 17; kt++) {
            __syncthreads();
            for (int e = tid; e < 16*64; e += 256) {
                int kk = e >> 6, rr = e & 63;
                int krow = kt*16 + kk;
                const float* src = (krow < 32) ? (plsb + (size_t)krow*H_)
                                               : (pb + (size_t)(krow - 32)*H_);
                prt[kk*64 + rr] = src[r0 + rr];
                if (!diag) pct[kk*64 + rr] = src[c0 + rr];
            }
            __syncthreads();
            const float* pcb = diag ? prt : pct;
            #pragma unroll
            for (int kk = 0; kk < 16; kk++) {
                float4 a4 = *(const float4*)&prt[kk*64 + tr*4];
                float4 b4 = *(const float4*)&pcb[kk*64 + tc*4];
                float av[4] = {a4.x, a4.y, a4.z, a4.w};
                float bv[4] = {b4.x, b4.y, b4.z, b4.w};
                #pragma unroll
                for (int i = 0; i < 4; i++)
                    #pragma unroll
                    for (int j = 0; j < 4; j++)
                        acc[i][j] += av[i]*bv[j];
            }
        }
        float* Gt = Gw + (size_t)b*GW_STR + (size_t)tile*4096;
        #pragma unroll
        for (int i = 0; i < 4; i++) {
            int lr = tr*4 + i;
            float v[4];
            #pragma unroll
            for (int j = 0; j < 4; j++) {
                int lc = tc*4 + j;
                v[j] = acc[i][j] + ((diag && lr == lc) ? LAM_ : 0.0f);
            }
            float4 o; o.x = v[0]; o.y = v[1]; o.z = v[2]; o.w = v[3];
            *(float4*)&Gt[lr*64 + tc*4] = o;
        }
    } else if (bx < 320) {
        if (tm < 0) return;
        const int b = bx - 256;
        float* xs  = smem;
        float* hs2 = smem + 16;
        float* gj  = smem + 144;
        float* gi  = smem + 272;
        float* gf  = smem + 400;
        float* go  = smem + 528;
        const int n = tid & 127, gg = tid >> 7;
        if (tid < 16)  xs[tid]  = x[(b*T_ + tm)*D_ + tid];
        if (tid < 128) hs2[tid] = h_mix[b*NU_ + tid];
        __syncthreads();
        const float* uA = gg ? uf : uj;
        const float* uB = gg ? uo : ui;
        const float* wA = gg ? wf : wj;
        const float* wB = gg ? wo : wi;
        float accA = gg ? bf_[n] : bj[n];
        float accB = gg ? bo[n]  : bi[n];
        #pragma unroll
        for (int d2 = 0; d2 < 16; ++d2) {
            float xv = xs[d2];
            accA += xv * uA[d2*NU_ + n];
            accB += xv * uB[d2*NU_ + n];
        }
        for (int m = 0; m < 128; ++m) {
            float hvv = hs2[m];
            accA += hvv * wA[m*NU_ + n];
            accB += hvv * wB[m*NU_ + n];
        }
        if (gg == 0) { gj[n] = tanhf(accA); gi[n] = sigm(accB); }
        else         { gf[n] = sigm(accA);  go[n] = sigm(accB); }
        __syncthreads();
        if (tid < 128) {
            float cn = gf[tid]*c_mix[b*NU_ + tid] + gi[tid]*gj[tid];
            c_mix[b*NU_ + tid] = cn;
            hml[b*NU_ + tid]   = go[tid]*tanhf(cn);
        }
    } else {
        if (te < 3) return;
        const int eb = bx - 320, b = eb >> 1, half = eb & 1;
        const int ts = te - 3;
        float* ys = smem;
        if (tid < 128) ys[tid] = ybuf[b*128 + tid];
        __syncthreads();
        const int k = half*136 + tid;
        if (tid < 136) {
            const float* rowp = (k < 32)
                ? pls + ((size_t)(te&3)*B_ + b)*PLS_STR + (size_t)k*H_
                : phi + (size_t)(te&1)*PHIBUF + (size_t)b*PHI_STR + (size_t)(k - 32)*H_;
            const float4* r4 = (const float4*)rowp;
            const float4* y4 = (const float4*)ys;
            float th = 0.f;
            for (int i4 = 0; i4 < 32; i4++) th += dot4(r4[i4], y4[i4]);
            if (k < 16)
                out[OFF_A + ts*(B_*D_) + b*D_ + k] = th;
            else if (k < 32)
                out[OFF_B + ts*(B_*D_) + b*D_ + (k - 16)] = th;
            else {
                int p = k - 32, ip = p/15, jj = p%15, jp = jj + (jj >= ip ? 1 : 0);
                out[OFF_G + ts*(B_*D_*D_) + b*(D_*D_) + ip*D_ + jp] = th;
            }
        }
        if (half == 0 && tid < 16)
            out[OFF_G + ts*(B_*D_*D_) + b*(D_*D_) + tid*D_ + tid] = 0.0f;
    }
}

__global__ __launch_bounds__(256) void k_Y8(
    const float* __restrict__ z, const float* __restrict__ at,
    const float* __restrict__ Wpsi, const float* __restrict__ bpsi,
    float* __restrict__ phi,
    const float* __restrict__ x, const float* __restrict__ hv,
    const float* __restrict__ Wj, const float* __restrict__ Wi, const float* __restrict__ Wf, const float* __restrict__ Wo,
    const float* __restrict__ Uj, const float* __restrict__ Ui, const float* __restrict__ Uf, const float* __restrict__ Uo,
    const float* __restrict__ Bj, const float* __restrict__ Bi, const float* __restrict__ Bf, const float* __restrict__ Bo,
    float* __restrict__ gates,
    const float* __restrict__ Gw, const float* __restrict__ hml, float* __restrict__ h_mix,
    const float* __restrict__ w_p, const float* __restrict__ b_p,
    float* __restrict__ ybuf, float* __restrict__ out,
    int tp, int tf, int tsolve)
{
    __shared__ __align__(16) float smem[17280];
    const int tid = threadIdx.x;
    const int bx = blockIdx.x;

    if (bx < 64) {
        const int b = bx;
        const int ts = tsolve;
        if (ts < 0) return;
        if (ts < 3) {
            if (tid < 128) h_mix[b*128 + tid] = hml[b*128 + tid];
            return;
        }
        float* Ac   = smem;
        float* rv   = smem + 16896;
        float* hm   = smem + 17024;
        float* dinv = smem + 17152;

        const int R = tid >> 4, C = tid & 15;
        const bool lower = (C <= R);

        if (tid < 128) { float v = hml[b*128 + tid]; hm[tid] = v; rv[tid] = v; }

        float g[8][8] = {};
        if (lower) {
            const int tsel = (C >= 8) ? 2 : ((R >= 8) ? 1 : 0);
            const float* Gt = Gw + (size_t)b*GW_STR + (size_t)tsel*4096;
            const int lcb = C*8 - ((C >= 8) ? 64 : 0);
            #pragma unroll
            for (int r = 0; r < 8; ++r) {
                const int lr = R*8 + r - ((R >= 8) ? 64 : 0);
                float4 lo = *(const float4*)(Gt + lr*64 + lcb);
                float4 hi = *(const float4*)(Gt + lr*64 + lcb + 4);
                g[r][0]=lo.x; g[r][1]=lo.y; g[r][2]=lo.z; g[r][3]=lo.w;
                g[r][4]=hi.x; g[r][5]=hi.y; g[r][6]=hi.z; g[r][7]=hi.w;
            }
        }

        for (int p = 0; p < 8; ++p) {
            const int s = p*16;
            if ((C >> 1) == p && R >= 2*p) {
                #pragma unroll
                for (int c = 0; c < 8; ++c) {
                    float4 lo = {g[0][c], g[1][c], g[2][c], g[3][c]};
                    float4 hi = {g[4][c], g[5][c], g[6][c], g[7][c]};
                    *(float4*)&Ac[(C*8 + c)*132 + R*8]     = lo;
                    *(float4*)&Ac[(C*8 + c)*132 + R*8 + 4] = hi;
                }
            }
            __syncthreads();
            if (tid < 64) {
                const int lane = tid;
                const int r0 = s + lane, r1 = r0 + 64;
                const bool v0 = r0 < 128, v1 = r1 < 128;
                float a0[16], a1[16];
                #pragma unroll
                for (int k = 0; k < 16; ++k) {
                    a0[k] = v0 ? Ac[(s+k)*132 + r0] : 0.f;
                    a1[k] = v1 ? Ac[(s+k)*132 + r1] : 0.f;
                }
                float myinv = 0.f;
                #pragma unroll
                for (int j = 0; j < 16; ++j) {
                    float piv = rdlane(a0[j], j);
                    float inv = rsqrtf(piv);
                    float dsq = piv * inv;
                    if (lane == j) myinv = inv;
                    a0[j] = (lane == j) ? dsq : a0[j]*inv;
                    a1[j] *= inv;
                    #pragma unroll
                    for (int c = j+1; c < 16; ++c) {
                        float Lcj = rdlane(a0[j], c);
                        a0[c] -= a0[j]*Lcj;
                        a1[c] -= a1[j]*Lcj;
                    }
                }
                if (lane < 16) dinv[s + lane] = myinv;
                float fr = (lane < 16) ? rv[s + lane] : 0.f;
                float yv[16];
                #pragma unroll
                for (int j = 0; j < 16; ++j) {
                    if (lane == j) fr *= myinv;
                    float yj = rdlane(fr, j);
                    if (lane > j && lane < 16) fr -= a0[j]*yj;
                    yv[j] = yj;
                }
                if (lane < 16) {
                    rv[r0] = fr;
                } else if (v0) {
                    float acc = rv[r0];
                    #pragma unroll
                    for (int k = 0; k < 16; ++k) acc -= a0[k]*yv[k];
                    rv[r0] = acc;
                }
                if (v1) {
                    float acc = rv[r1];
                    #pragma unroll
                    for (int k = 0; k < 16; ++k) acc -= a1[k]*yv[k];
                    rv[r1] = acc;
                }
                #pragma unroll
                for (int k = 0; k < 16; ++k) {
                    if (v0) Ac[(s+k)*132 + r0] = a0[k];
                    if (v1) Ac[(s+k)*132 + r1] = a1[k];
                }
            }
            __syncthreads();
            if (lower && C >= 2*(p+1)) {
                #pragma unroll
                for (int k = 0; k < 16; ++k) {
                    const float* colp = &Ac[(s+k)*132];
                    float4 r04 = *(const float4*)&colp[R*8];
                    float4 r14 = *(const float4*)&colp[R*8 + 4];
                    float4 c04 = *(const float4*)&colp[C*8];
                    float4 c14 = *(const float4*)&colp[C*8 + 4];
                    float lr[8] = {r04.x,r04.y,r04.z,r04.w,r14.x,r14.y,r14.z,r14.w};
                    float lc[8] = {c04.x,c04.y,c04.z,c04.w,c14.x,c14.y,c14.z,c14.w};
                    #pragma unroll
                    for (int r = 0; r < 8; ++r)
                        #pragma unroll
                        for (int c = 0; c < 8; ++c)
                            g[r][c] -= lr[r]*lc[c];
                }
            }
        }

        if (tid >= 64) return;
        const int lane = tid;
        for (int p = 7; p >= 0; --p) {
            const int s = p*16;
            float br = 0.f, minv = 0.f;
            float lc[16];
            if (lane < 16) {
                br = rv[s + lane];
                minv = dinv[s + lane];
                #pragma unroll
                for (int k4 = 0; k4 < 4; ++k4) {
                    float4 f4 = *(const float4*)&Ac[(s+lane)*132 + s + k4*4];
                    lc[k4*4+0]=f4.x; lc[k4*4+1]=f4.y; lc[k4*4+2]=f4.z; lc[k4*4+3]=f4.w;
                }
            } else {
                #pragma unroll
                for (int k = 0; k < 16; ++k) lc[k] = 0.f;
            }
            float xk[16];
            #pragma unroll
            for (int j = 15; j >= 0; --j) {
                if (lane == j) br *= minv;
                float xj = rdlane(br, j);
                if (lane < j) br -= lc[j]*xj;
                xk[j] = xj;
            }
            if (lane < 16) rv[s + lane] = br;
            for (int i = lane; i < s; i += 64) {
                float acc = rv[i];
                #pragma unroll
                for (int k4 = 0; k4 < 4; ++k4) {
                    float4 f4 = *(const float4*)&Ac[i*132 + s + k4*4];
                    acc -= f4.x*xk[k4*4] + f4.y*xk[k4*4+1] + f4.z*xk[k4*4+2] + f4.w*xk[k4*4+3];
                }
                rv[i] = acc;
            }
        }

        float pw = 0.f;
        #pragma unroll
        for (int ii = 0; ii < 2; ++ii) {
            int i = lane + ii*64;
            float y = rv[i];
            float hhat = hm[i] - LAM_ * y;
            h_mix[b*128 + i] = hhat;
            ybuf[b*128 + i] = y;
            pw += hhat * w_p[i];
        }
        for (int off = 32; off; off >>= 1) pw += __shfl_down(pw, off);
        if (lane == 0) out[b*NSTEP_OUT + (ts - 3)] = pw + b_p[0];
    } else if (bx < 384) {
        if (tp < 0) return;
        const int pc = (bx - 64) >> 6, b = (bx - 64) & 63;
        const int p0 = pc * 48;
        float* zs = smem;
        float* pr = smem + 2048;
        {
            const float4* zsrc = (const float4*)(z + b*2048);
            #pragma unroll
            for (int i = 0; i < 2; ++i) ((float4*)zs)[i*256 + tid] = zsrc[i*256 + tid];
        }
        __syncthreads();
        for (int e = tid; e < 48*128; e += 256) {
            int pp = e >> 7, c = e & 127;
            int p = p0 + pp, ip = p/15, jj2 = p%15, jp = jj2 + (jj2 >= ip ? 1 : 0);
            pr[pp*128 + c] = zs[ip*128 + c] * zs[jp*128 + c];
        }
        __syncthreads();
        const int hg = tid & 31, pg = tid >> 5;
        const int h0 = hg*4, pp0 = pg*6;
        const float4* w0 = (const float4*)(Wpsi + (size_t)(h0+0)*H_);
        const float4* w1 = (const float4*)(Wpsi + (size_t)(h0+1)*H_);
        const float4* w2 = (const float4*)(Wpsi + (size_t)(h0+2)*H_);
        const float4* w3 = (const float4*)(Wpsi + (size_t)(h0+3)*H_);
        float acc[6][4] = {};
        for (int i4 = 0; i4 < 32; i4++) {
            float4 wa = w0[i4], wb = w1[i4], wc = w2[i4], wd = w3[i4];
            #pragma unroll
            for (int r = 0; r < 6; r++) {
                float4 p4 = *(const float4*)&pr[(pp0 + r)*128 + i4*4];
                acc[r][0] += dot4(wa, p4);
                acc[r][1] += dot4(wb, p4);
                acc[r][2] += dot4(wc, p4);
                acc[r][3] += dot4(wd, p4);
            }
        }
        float4 bb = *(const float4*)&bpsi[h0];
        float* phb = phi + (size_t)(tp&1)*PHIBUF + (size_t)b*PHI_STR;
        #pragma unroll
        for (int r = 0; r < 6; r++) {
            int pp = pp0 + r, p = p0 + pp;
            int ip = p/15, jj2 = p%15, jp = jj2 + (jj2 >= ip ? 1 : 0);
            float wat = at[b*256 + ip*16 + jp];
            float4 o;
            o.x = tanhf(acc[r][0] + bb.x) * wat;
            o.y = tanhf(acc[r][1] + bb.y) * wat;
            o.z = tanhf(acc[r][2] + bb.z) * wat;
            o.w = tanhf(acc[r][3] + bb.w) * wat;
            *(float4*)&phb[(size_t)p*H_ + h0] = o;
        }
    } else {
        if (tf < 0 || tf > T_ - 2) return;
        float* hsT = smem;
        float* Ws  = smem + 8704;
        const int fbx = bx - 384;
        const int kh = fbx & 1, g = (fbx >> 1) & 3, d = fbx >> 3;
        const int k0 = kh * 64;
        const float* W  = (g==0?Wj:(g==1?Wi:(g==2?Wf:Wo))) + (size_t)d*H_*H_;
        const float* U  = (g==0?Uj:(g==1?Ui:(g==2?Uf:Uo))) + d*H_;
        const float* Bp = (g==0?Bj:(g==1?Bi:(g==2?Bf:Bo))) + d*H_;

        for (int e = tid; e < 64*128; e += 256) {
            int b2 = e >> 7, h2 = e & 127;
            hsT[h2*68 + b2] = hv[(b2*D_ + d)*H_ + h2];
        }
        const int tb = tid >> 4, tk = tid & 15;
        float acc[4][4] = {};
        for (int hc = 0; hc < 2; hc++) {
            __syncthreads();
            for (int e = tid; e < 64*64; e += 256) {
                int h2 = e >> 6, kk = e & 63;
                Ws[h2*64 + kk] = W[(hc*64 + h2)*H_ + k0 + kk];
            }
            __syncthreads();
            for (int h2 = 0; h2 < 64; h2++) {
                float4 hb = *(const float4*)&hsT[(hc*64 + h2)*68 + tb*4];
                float4 wk = *(const float4*)&Ws[h2*64 + tk*4];
                float hbv[4] = {hb.x, hb.y, hb.z, hb.w};
                float wkv[4] = {wk.x, wk.y, wk.z, wk.w};
                #pragma unroll
                for (int a2 = 0; a2 < 4; a2++)
                    #pragma unroll
                    for (int c2 = 0; c2 < 4; c2++)
                        acc[a2][c2] += hbv[a2] * wkv[c2];
            }
        }
        float u4[4], bp4[4];
        #pragma unroll
        for (int c2 = 0; c2 < 4; c2++) { u4[c2] = U[k0 + tk*4 + c2]; bp4[c2] = Bp[k0 + tk*4 + c2]; }
        #pragma unroll
        for (int a2 = 0; a2 < 4; a2++) {
            int b2 = tb*4 + a2;
            float xv = x[(b2*T_ + tf)*D_ + d];
            float4 o;
            float pre[4];
            #pragma unroll
            for (int c2 = 0; c2 < 4; c2++) pre[c2] = acc[a2][c2] + xv*u4[c2] + bp4[c2];
            if (g == 0) { o.x = tanhf(pre[0]); o.y = tanhf(pre[1]); o.z = tanhf(pre[2]); o.w = tanhf(pre[3]); }
            else        { o.x = sigm(pre[0]);  o.y = sigm(pre[1]);  o.z = sigm(pre[2]);  o.w = sigm(pre[3]); }
            *(float4*)&gates[(size_t)g*(B_*D_*H_) + (b2*D_ + d)*H_ + k0 + tk*4] = o;
        }
    }
}

// ---------------------------------------------------------------------------
extern "C" void kernel_launch(void* const* d_in, const int* in_sizes, int n_in,
                              void* d_out, int out_size, void* d_ws, size_t ws_size,
                              hipStream_t stream) {
    const float* x    = (const float*)d_in[0];
    const float* W_j  = (const float*)d_in[1];
    const float* W_i  = (const float*)d_in[2];
    const float* W_f  = (const float*)d_in[3];
    const float* W_o  = (const float*)d_in[4];
    const float* U_j  = (const float*)d_in[5];
    const float* U_i  = (const float*)d_in[6];
    const float* U_f  = (const float*)d_in[7];
    const float* U_o  = (const float*)d_in[8];
    const float* B_j  = (const float*)d_in[9];
    const float* B_i  = (const float*)d_in[10];
    const float* B_f  = (const float*)d_in[11];
    const float* B_o  = (const float*)d_in[12];
    const float* u_j  = (const float*)d_in[13];
    const float* u_i  = (const float*)d_in[14];
    const float* u_f  = (const float*)d_in[15];
    const float* u_o  = (const float*)d_in[16];
    const float* w_j  = (const float*)d_in[17];
    const float* w_i  = (const float*)d_in[18];
    const float* w_f  = (const float*)d_in[19];
    const float* w_o  = (const float*)d_in[20];
    const float* b_j  = (const float*)d_in[21];
    const float* b_i  = (const float*)d_in[22];
    const float* b_f  = (const float*)d_in[23];
    const float* b_o  = (const float*)d_in[24];
    const float* W_qkv= (const float*)d_in[25];
    const float* W_out= (const float*)d_in[26];
    const float* W_psi= (const float*)d_in[27];
    const float* b_psi= (const float*)d_in[28];
    const float* w_p  = (const float*)d_in[29];
    const float* b_p  = (const float*)d_in[30];

    float* out = (float*)d_out;
    float* ws = (float*)d_ws;

    const size_t NEED = (size_t)11640832 * 4;   // 46.6 MB

    if (ws_size >= NEED) {
        // ================= pipelined path =================
        float* hv    = ws;                   // 131072
        float* cv    = hv + 131072;          // 131072
        float* h_mix = cv + 131072;          // 8192
        float* c_mix = h_mix + 8192;         // 8192
        float* hml   = c_mix + 8192;         // 8192
        float* gates = hml + 8192;           // 524288
        float* zbuf  = gates + 524288;       // 131072
        float* atbuf = zbuf + 131072;        // 16384
        float* pls   = atbuf + 16384;        // 4*262144
        float* phi   = pls + 4*262144;       // 3*1966080
        float* Gring = phi + (size_t)3*1966080; // 2*786432
        float* Lring = Gring + 2*786432;     // 2*1081344

        hipMemsetAsync(ws, 0, (size_t)286720 * sizeof(float), stream);

        #define LAUNCH_P(tt) k_P<<<320, 256, 0, stream>>>( \
            hv, cv, gates, pls, W_qkv, W_out, zbuf, atbuf, phi, Gring, Lring, \
            hml, h_mix, w_p, b_p, out, (tt))
        #define LAUNCH_Q(tt) k_Q<<<640, 256, 0, stream>>>( \
            zbuf, atbuf, W_psi, b_psi, phi, x, hv, \
            W_j, W_i, W_f, W_o, U_j, U_i, U_f, U_o, B_j, B_i, B_f, B_o, gates, \
            Gring, Lring, h_mix, c_mix, hml, \
            u_j, u_i, u_f, u_o, w_j, w_i, w_f, w_o, b_j, b_i, b_f, b_o, (tt))

        // prologue: prime the var-chain 2 steps ahead
        LAUNCH_Q(-3);   // front(0)
        LAUNCH_P(-2);   // attn(0)
        LAUNCH_Q(-2);   // front(1)
        LAUNCH_P(-1);   // attn(1)
        LAUNCH_Q(-1);   // front(2)

        for (int t = 0; t <= 47; ++t) {
            LAUNCH_P(t);
            if (t < 47) LAUNCH_Q(t);
        }
        #undef LAUNCH_P
        #undef LAUNCH_Q
    } else {
        // ================= fallback: round-8 path =================
        float* h_var = ws;                       // 131072
        float* c_var = h_var + 131072;           // 131072
        float* h_mix = c_var + 131072;           // 8192
        float* c_mix = h_mix + 8192;             // 8192
        float* hml   = c_mix + 8192;             // 8192
        float* gates = hml + 8192;               // 524288
        float* phi   = gates + 524288;           // 2*PHIBUF
        float* zbuf  = phi + 3932160;            // 131072
        float* atbuf = zbuf + 131072;            // 16384
        float* Gw    = atbuf + 16384;            // 786432
        float* pls   = Gw + 786432;              // 1048576
        float* ybuf  = pls + 1048576;            // 8192

        hipMemsetAsync(ws, 0, (size_t)278528 * sizeof(float), stream);

        k_Y8<<<512, 256, 0, stream>>>(
            zbuf, atbuf, W_psi, b_psi, phi, x, h_var,
            W_j, W_i, W_f, W_o, U_j, U_i, U_f, U_o, B_j, B_i, B_f, B_o, gates,
            Gw, hml, h_mix, w_p, b_p, ybuf, out, -1, 0, -1);

        for (int t = 0; t < T_ - 1; t++) {
            k_X8<<<448, 256, 0, stream>>>(
                h_var, c_var, gates, pls, W_qkv, W_out, zbuf, atbuf,
                phi, Gw, x, h_mix, c_mix, hml,
                u_j, u_i, u_f, u_o, w_j, w_i, w_f, w_o, b_j, b_i, b_f, b_o,
                ybuf, out, t, t - 1, t - 1, t - 2);
            k_Y8<<<512, 256, 0, stream>>>(
                zbuf, atbuf, W_psi, b_psi, phi, x, h_var,
                W_j, W_i, W_f, W_o, U_j, U_i, U_f, U_o, B_j, B_i, B_f, B_o, gates,
                Gw, hml, h_mix, w_p, b_p, ybuf, out, t, t + 1, t - 1);
        }
        k_X8<<<448, 256, 0, stream>>>(
            h_var, c_var, gates, pls, W_qkv, W_out, zbuf, atbuf,
            phi, Gw, x, h_mix, c_mix, hml,
            u_j, u_i, u_f, u_o, w_j, w_i, w_f, w_o, b_j, b_i, b_f, b_o,
            ybuf, out, -1, T_ - 2, T_ - 2, T_ - 3);
        k_Y8<<<512, 256, 0, stream>>>(
            zbuf, atbuf, W_psi, b_psi, phi, x, h_var,
            W_j, W_i, W_f, W_o, U_j, U_i, U_f, U_o, B_j, B_i, B_f, B_o, gates,
            Gw, hml, h_mix, w_p, b_p, ybuf, out, -1, -1, T_ - 2);
        k_X8<<<448, 256, 0, stream>>>(
            h_var, c_var, gates, pls, W_qkv, W_out, zbuf, atbuf,
            phi, Gw, x, h_mix, c_mix, hml,
            u_j, u_i, u_f, u_o, w_j, w_i, w_f, w_o, b_j, b_i, b_f, b_o,
            ybuf, out, -1, -1, -1, T_ - 2);
    }
}